// Round 12
// baseline (178.054 us; speedup 1.0000x reference)
//
#include <hip/hip_runtime.h>
#include <hip/hip_bf16.h>
#include <stdint.h>

#define BB 4
#define TT 2048
#define DD 1024
#define HH 16
#define MTOK (BB*TT)
#define NQ 4096            // q|k|v|g concat width
#define NW (NQ+128)        // wcat rows incl. small-proj block
#define TC 32              // scan chunk length
#define NC (TT/TC)         // 64 chunks
#define BH (BB*HH)         // 64
#define ROWT (16*NQ)       // elements per 16-row blocked stripe

typedef __bf16 bf16x8 __attribute__((ext_vector_type(8)));
typedef float f32x4 __attribute__((ext_vector_type(4)));

__device__ __forceinline__ uint16_t f2bf(float f){
  uint32_t u = __float_as_uint(f);
  u += 0x7fffu + ((u >> 16) & 1u);
  return (uint16_t)(u >> 16);
}
__device__ __forceinline__ float bf2f(uint32_t h){ return __uint_as_float(h << 16); }
// sigmoid via fast exp + raw v_rcp_f32 (1 ulp) -- avoids precise-div expansion
__device__ __forceinline__ float sigm(float z){
  return __builtin_amdgcn_rcpf(1.f + __expf(-z));
}

__device__ __forceinline__ void gll16(const uint16_t* src, uint16_t* dst){
  __builtin_amdgcn_global_load_lds(
      (const __attribute__((address_space(1))) void*)src,
      (__attribute__((address_space(3))) void*)dst, 16, 0, 0);
}
// extract bf16 element e (static) from a uint4 (8 bf16)
__device__ __forceinline__ float bfel(const uint4& v, int e){
  uint32_t wrd = ((e>>1)==0) ? v.x : ((e>>1)==1) ? v.y : ((e>>1)==2) ? v.z : v.w;
  return bf2f((e&1) ? (wrd >> 16) : (wrd & 0xffffu));
}

// ---------------- prep: pure casts ----------------
// blocks [0,5120): Wq|Wk|Wv|Wg -> wcat rows 0..4095, Wo -> wob  (1 float4/thr)
// blocks [5120,9216): x -> xb  (2 float4/thr)
// blocks [9216,9344): Wb|Wfd|Wsd|zeros -> wcat rows 4096..4223  (4 elems/thr)
__global__ __launch_bounds__(256) void prep_kernel(
    const float* __restrict__ x,
    const float* __restrict__ Wq, const float* __restrict__ Wk,
    const float* __restrict__ Wv, const float* __restrict__ Wg,
    const float* __restrict__ Wo,
    const float* __restrict__ Wb, const float* __restrict__ Wfd,
    const float* __restrict__ Wsd,
    uint16_t* __restrict__ wcat, uint16_t* __restrict__ wob,
    uint16_t* __restrict__ xb)
{
  const int bx = blockIdx.x;
  if (bx < 5120){
    int i = bx * 256 + threadIdx.x;      // float4 index; 262144 per weight
    int wsel = i >> 18;
    int loc = i & 262143;
    const float* src = (wsel == 0) ? Wq : (wsel == 1) ? Wk : (wsel == 2) ? Wv : (wsel == 3) ? Wg : Wo;
    uint16_t* dst = (wsel < 4) ? (wcat + (size_t)wsel * DD * DD) : wob;
    float4 v = ((const float4*)src)[loc];
    ushort4 o;
    o.x = f2bf(v.x); o.y = f2bf(v.y); o.z = f2bf(v.z); o.w = f2bf(v.w);
    ((ushort4*)dst)[loc] = o;
  } else if (bx < 9216){
    int base = (bx - 5120) * 512 + threadIdx.x;
    #pragma unroll
    for (int rep = 0; rep < 2; rep++){
      int loc = base + rep * 256;
      float4 v = ((const float4*)x)[loc];
      ushort4 o;
      o.x = f2bf(v.x); o.y = f2bf(v.y); o.z = f2bf(v.z); o.w = f2bf(v.w);
      ((ushort4*)xb)[loc] = o;
    }
  } else {
    int u = (bx - 9216) * 256 + threadIdx.x;   // 4-elem unit; 256 units/row
    int row = u >> 8;
    int cidx = (u & 255) * 4;
    ushort4 o = {0, 0, 0, 0};
    if (row < 48){
      const float* src = (row < 16) ? (Wb + (size_t)row * DD)
                       : (row < 32) ? (Wfd + (size_t)(row - 16) * DD)
                                    : (Wsd + (size_t)(row - 32) * DD);
      float4 v = *(const float4*)(src + cidx);
      o.x = f2bf(v.x); o.y = f2bf(v.y); o.z = f2bf(v.z); o.w = f2bf(v.w);
    }
    *(ushort4*)(wcat + (size_t)(NQ + row) * DD + cidx) = o;
  }
}

// =============== 128x128 GEMM, BK=64, m97 2-barrier structure ===============
// X:[M][K], W:[N][K] bf16 row-major. 256 thr = 4 waves (2x2), 64x64 per wave.
// LDS 2x16KB single-buffered. Per-8-row XOR swizzle on 16B chunks:
// LDS chunk p holds logical (row=p>>3, quarter=(p&7)^(row&7)); inverse applied
// to the global source of global_load_lds (rule #21) -> 0 bank conflicts.
// MODE 0 (grid 32 x 66): unified qkvg + small-proj dispatch.
//   blockIdx.y < 2:  small-proj block. m-tile = y*32+x, B = W + NQ*DD (rows
//                    4096..4223), n0 = 0. Epilogue: sigm(v+bias) -> sc f32
//                    [3][B][H][T] (cols 0..47; rest discarded). Dispatched
//                    FIRST so the 64 blocks overlap the main schedule.
//   blockIdx.y >= 2: main qkvg tile, m0=(y-2)*128, n0=x*128. Main linear IDs
//                    shift by 64 == 0 mod 8 -> XCD alignment of R11 preserved.
//   Epilogue: silu (n0<3072) / sigmoid -> blocked bf16 Y.
// MODE 1: plain f32 row-major out, no activation (2D grid, x=8 tiles).
template<int MODE>
__global__ __launch_bounds__(256) void gemm128(
    const uint16_t* __restrict__ X, const uint16_t* __restrict__ W,
    uint16_t* __restrict__ Y, float* __restrict__ Yf,
    const float* __restrict__ bfd, const float* __restrict__ bsd,
    float* __restrict__ scp, int N, int K)
{
  __shared__ __align__(16) uint16_t lA[128 * 64];
  __shared__ __align__(16) uint16_t lB[128 * 64];
  const int tid = threadIdx.x;
  const bool smallBlk = (MODE == 0) && (blockIdx.y < 2);
  const int m0 = smallBlk ? (blockIdx.y * 32 + blockIdx.x) * 128
                          : (MODE == 0 ? (blockIdx.y - 2) * 128 : blockIdx.y * 128);
  const int n0 = smallBlk ? 0 : blockIdx.x * 128;
  const uint16_t* Wb_ = smallBlk ? (W + (size_t)NQ * DD) : W;
  const int l = tid & 63, w = tid >> 6;
  const int wr = w >> 1, wc = w & 1;
  const int g = l >> 4, r16 = l & 15;

  // staging: chunk p = n*256 + tid; row = p>>3, logical quarter = (p&7)^(row&7)
  const uint16_t* srcA[4];
  const uint16_t* srcB[4];
  uint16_t* dstA[4];
  uint16_t* dstB[4];
  #pragma unroll
  for (int n = 0; n < 4; n++){
    int p = n * 256 + tid;
    int row = p >> 3;
    int cq = (p & 7) ^ (row & 7);
    srcA[n] = X + (size_t)(m0 + row) * K + cq * 8;
    srcB[n] = Wb_ + (size_t)(n0 + row) * K + cq * 8;
    int basechunk = n * 256 + (tid & ~63);     // wave-uniform
    dstA[n] = lA + basechunk * 8;
    dstB[n] = lB + basechunk * 8;
  }

  // frag read offsets (u16 idx): row*64 + ((ks*4+g)^(row&7))*8
  int roA[4][2], roB[4][2];
  #pragma unroll
  for (int i = 0; i < 4; i++)
    #pragma unroll
    for (int ks = 0; ks < 2; ks++){
      roA[i][ks] = (wr * 64 + i * 16 + r16) * 64 + ((ks * 4 + g) ^ (r16 & 7)) * 8;
      roB[i][ks] = (wc * 64 + i * 16 + r16) * 64 + ((ks * 4 + g) ^ (r16 & 7)) * 8;
    }

  f32x4 acc[4][4];
  #pragma unroll
  for (int i = 0; i < 4; i++)
    #pragma unroll
    for (int j = 0; j < 4; j++) acc[i][j] = (f32x4){0.f, 0.f, 0.f, 0.f};

  for (int kt = 0; kt < K; kt += 64){
    __syncthreads();                    // WAR: prior tile reads done
    #pragma unroll
    for (int n = 0; n < 4; n++){
      gll16(srcA[n] + kt, dstA[n]);
      gll16(srcB[n] + kt, dstB[n]);
    }
    __syncthreads();                    // compiler drains vmcnt(0) before barrier

    #pragma unroll
    for (int ks = 0; ks < 2; ks++){
      bf16x8 af[4], bw[4];
      #pragma unroll
      for (int mi = 0; mi < 4; mi++) af[mi] = *(const bf16x8*)(lA + roA[mi][ks]);
      #pragma unroll
      for (int ni = 0; ni < 4; ni++) bw[ni] = *(const bf16x8*)(lB + roB[ni][ks]);
      #pragma unroll
      for (int mi = 0; mi < 4; mi++)
        #pragma unroll
        for (int ni = 0; ni < 4; ni++)
          acc[mi][ni] = __builtin_amdgcn_mfma_f32_16x16x32_bf16(af[mi], bw[ni], acc[mi][ni], 0, 0, 0);
    }
  }

  // C/D layout: col=lane&15, row=(lane>>4)*4+reg  [m89-verified]
  if (MODE == 0){
    if (!smallBlk){
      const bool dosig = (n0 >= 3 * DD);
      #pragma unroll
      for (int mi = 0; mi < 4; mi++){
        const int R0 = m0 + wr * 64 + mi * 16;
        const size_t rbase = (size_t)(R0 >> 4) * ROWT;
        #pragma unroll
        for (int ni = 0; ni < 4; ni++){
          const int C0 = n0 + wc * 64 + ni * 16;
          f32x4 v = acc[mi][ni];
          float o[4];
          #pragma unroll
          for (int r = 0; r < 4; r++){
            float xx = v[r];
            o[r] = dosig ? sigm(xx) : xx * sigm(xx);
          }
          uint2 pk;
          pk.x = (uint32_t)f2bf(o[0]) | ((uint32_t)f2bf(o[1]) << 16);
          pk.y = (uint32_t)f2bf(o[2]) | ((uint32_t)f2bf(o[3]) << 16);
          size_t off = rbase + (size_t)(C0 >> 4) * 256 + (size_t)r16 * 16 + g * 4;
          *(uint2*)(Y + off) = pk;
        }
      }
    } else {
      // small-proj: cols 0..47 -> sc[grp][b][h][t] (f32), cols 48..127 discarded
      #pragma unroll
      for (int ni = 0; ni < 4; ni++){
        const int cc0 = wc * 64 + ni * 16;          // col block within tile
        const int grp = cc0 >> 4;
        if (grp < 3){
          const int h = r16;
          const float bias = (grp == 0) ? 0.f : (grp == 1) ? bfd[h] : bsd[h];
          #pragma unroll
          for (int mi = 0; mi < 4; mi++){
            const int R0 = m0 + wr * 64 + mi * 16 + g * 4;  // token rows R0..R0+3
            const int b = R0 >> 11, t = R0 & (TT - 1);
            f32x4 v = acc[mi][ni];
            float4 o;
            o.x = sigm(v[0] + bias);
            o.y = sigm(v[1] + bias);
            o.z = sigm(v[2] + bias);
            o.w = sigm(v[3] + bias);
            *(float4*)(scp + (((size_t)grp * BB + b) * HH + h) * TT + t) = o;
          }
        }
      }
    }
  } else {
    #pragma unroll
    for (int mi = 0; mi < 4; mi++){
      #pragma unroll
      for (int ni = 0; ni < 4; ni++){
        int rg = m0 + wr * 64 + mi * 16 + g * 4;
        int cg = n0 + wc * 64 + ni * 16 + r16;
        #pragma unroll
        for (int r = 0; r < 4; r++)
          Yf[(size_t)(rg + r) * N + cg] = acc[mi][ni][r];
      }
    }
  }
}

// ---------------- chunked scan over blocked qkvg ----------------
// blocked elem(R,C) = (R>>4)*ROWT + (C>>4)*256 + (C&15)*16 + (R&15)
// step: [sf,ss]' = M_t [sf,ss] + 1.05*u_t*[1,1],  M_t = [[f,.05s],[.05f,s]]

// Pass A: per (chunk j, bh): zero-entry local end state L + chunk 2x2 matrix P
__global__ __launch_bounds__(64) void scan_partA(
    const uint16_t* __restrict__ qkvg, const float* __restrict__ sc,
    float* __restrict__ Lst, float4* __restrict__ Pm)
{
  int j = blockIdx.x, bh = blockIdx.y;
  int b = bh >> 4, h = bh & 15;
  int c = threadIdx.x;
  const int ci = c & 15;
  const size_t tc_k = (size_t)((DD     + h * 64 + c) >> 4) * 256 + ci * 16;
  const size_t tc_v = (size_t)((2 * DD + h * 64 + c) >> 4) * 256 + ci * 16;
  const float* bet = sc + ((size_t)(0 * BB + b) * HH + h) * TT + j * TC;
  const float* fdp = sc + ((size_t)(1 * BB + b) * HH + h) * TT + j * TC;
  const float* sdp = sc + ((size_t)(2 * BB + b) * HH + h) * TT + j * TC;

  float sf = 0.f, ss = 0.f;
  float p00 = 1.f, p01 = 0.f, p10 = 0.f, p11 = 1.f;
  #pragma unroll
  for (int t16 = 0; t16 < 2; ++t16){
    int R0 = b * TT + j * TC + t16 * 16;
    size_t tb = (size_t)(R0 >> 4) * ROWT;
    uint4 kl = *(const uint4*)(qkvg + tb + tc_k);
    uint4 kh = *(const uint4*)(qkvg + tb + tc_k + 8);
    uint4 vl = *(const uint4*)(qkvg + tb + tc_v);
    uint4 vh = *(const uint4*)(qkvg + tb + tc_v + 8);
    const float* bt = bet + t16 * 16;
    const float* ft = fdp + t16 * 16;
    const float* st = sdp + t16 * 16;
    #pragma unroll
    for (int u = 0; u < 16; ++u){
      float kv = (u < 8) ? bfel(kl, u) : bfel(kh, u - 8);
      float vv = (u < 8) ? bfel(vl, u) : bfel(vh, u - 8);
      float btv = bt[u], f = ft[u], s = st[u];
      float uu = 1.05f * btv * kv * vv;
      float bq = 0.05f * s, cq = 0.05f * f;
      float nf = f * sf + bq * ss + uu;
      float ns = cq * sf + s * ss + uu;
      sf = nf; ss = ns;
      float q00 = f * p00 + bq * p10, q01 = f * p01 + bq * p11;
      float q10 = cq * p00 + s * p10, q11 = cq * p01 + s * p11;
      p00 = q00; p01 = q01; p10 = q10; p11 = q11;
    }
  }
  size_t base = ((size_t)bh * NC + j) * 2;
  Lst[(base + 0) * 64 + c] = sf;
  Lst[(base + 1) * 64 + c] = ss;
  if (c == 0) Pm[(size_t)bh * NC + j] = make_float4(p00, p01, p10, p11);
}

// Pass C (with folded lookback): compute entry state E_j from Lst/Pm (all
// written by partA, complete at kernel boundary -- deterministic, no atomics),
// then replay chunk and write og row-major via LDS micro-transpose.
__global__ __launch_bounds__(64) void scan_partC(
    const uint16_t* __restrict__ qkvg, const float* __restrict__ sc,
    const float* __restrict__ Lst, const float4* __restrict__ Pm,
    uint16_t* __restrict__ og)
{
  __shared__ uint16_t ot[16 * 64];
  int j = blockIdx.x, bh = blockIdx.y;
  int b = bh >> 4, h = bh & 15;
  int c = threadIdx.x;
  const int ci = c & 15;

  // forward lookback: E = P_i * E + L_i for i = 0..j-1
  float sf = 0.f, ss = 0.f;
  for (int i = 0; i < j; ++i){
    size_t pbase = ((size_t)bh * NC + i) * 2;
    float lf = Lst[(pbase + 0) * 64 + c];
    float ls = Lst[(pbase + 1) * 64 + c];
    float4 P = Pm[(size_t)bh * NC + i];
    float nf = P.x * sf + P.y * ss + lf;
    float ns = P.z * sf + P.w * ss + ls;
    sf = nf; ss = ns;
  }

  const size_t tc_q = (size_t)((         h * 64 + c) >> 4) * 256 + ci * 16;
  const size_t tc_k = (size_t)((DD     + h * 64 + c) >> 4) * 256 + ci * 16;
  const size_t tc_v = (size_t)((2 * DD + h * 64 + c) >> 4) * 256 + ci * 16;
  const size_t tc_g = (size_t)((3 * DD + h * 64 + c) >> 4) * 256 + ci * 16;
  const float* bet = sc + ((size_t)(0 * BB + b) * HH + h) * TT + j * TC;
  const float* fdp = sc + ((size_t)(1 * BB + b) * HH + h) * TT + j * TC;
  const float* sdp = sc + ((size_t)(2 * BB + b) * HH + h) * TT + j * TC;

  #pragma unroll
  for (int t16 = 0; t16 < 2; ++t16){
    int R0 = b * TT + j * TC + t16 * 16;
    size_t tb = (size_t)(R0 >> 4) * ROWT;
    uint4 ql = *(const uint4*)(qkvg + tb + tc_q);
    uint4 qh = *(const uint4*)(qkvg + tb + tc_q + 8);
    uint4 kl = *(const uint4*)(qkvg + tb + tc_k);
    uint4 kh = *(const uint4*)(qkvg + tb + tc_k + 8);
    uint4 vl = *(const uint4*)(qkvg + tb + tc_v);
    uint4 vh = *(const uint4*)(qkvg + tb + tc_v + 8);
    uint4 gl = *(const uint4*)(qkvg + tb + tc_g);
    uint4 gh = *(const uint4*)(qkvg + tb + tc_g + 8);
    const float* bt = bet + t16 * 16;
    const float* ft = fdp + t16 * 16;
    const float* st = sdp + t16 * 16;
    #pragma unroll
    for (int u = 0; u < 16; ++u){
      float qv = (u < 8) ? bfel(ql, u) : bfel(qh, u - 8);
      float kv = (u < 8) ? bfel(kl, u) : bfel(kh, u - 8);
      float vv = (u < 8) ? bfel(vl, u) : bfel(vh, u - 8);
      float gv = (u < 8) ? bfel(gl, u) : bfel(gh, u - 8);
      float btv = bt[u], f = ft[u], s = st[u];
      sf *= f; ss *= s;
      float o = 0.5f * qv * (sf + ss);
      float uu = btv * kv * vv;
      sf += uu; ss += uu;
      float nf = sf + 0.05f * ss, ns = ss + 0.05f * sf;
      sf = nf; ss = ns;
      ot[u * 64 + c] = f2bf(o * gv);
    }
    __syncthreads();
    {
      int u0 = c >> 3, c8 = c & 7;
      uint4 d0 = *(const uint4*)&ot[u0 * 64 + c8 * 8];
      uint4 d1 = *(const uint4*)&ot[(u0 + 8) * 64 + c8 * 8];
      uint16_t* ob = og + (size_t)R0 * DD + h * 64 + c8 * 8;
      *(uint4*)(ob + (size_t)u0 * DD) = d0;
      *(uint4*)(ob + (size_t)(u0 + 8) * DD) = d1;
    }
    __syncthreads();
  }
}

extern "C" void kernel_launch(void* const* d_in, const int* in_sizes, int n_in,
                              void* d_out, int out_size, void* d_ws, size_t ws_size,
                              hipStream_t stream)
{
  const float* x   = (const float*)d_in[0];
  const float* Wq  = (const float*)d_in[1];
  const float* Wk  = (const float*)d_in[2];
  const float* Wv  = (const float*)d_in[3];
  const float* Wo  = (const float*)d_in[4];
  const float* Wb  = (const float*)d_in[5];
  const float* Wfd = (const float*)d_in[6];
  const float* bfd = (const float*)d_in[7];
  const float* Wsd = (const float*)d_in[8];
  const float* bsd = (const float*)d_in[9];
  const float* Wg  = (const float*)d_in[10];
  float* out = (float*)d_out;

  char* ws = (char*)d_ws;
  size_t off = 0;
  auto alloc = [&](size_t bytes) -> void* {
    void* p = ws + off;
    off += (bytes + 255) & ~(size_t)255;
    return p;
  };

  uint16_t* xb   = (uint16_t*)alloc((size_t)MTOK * DD * 2);   // doubles as ogb later
  uint16_t* wcat = (uint16_t*)alloc((size_t)NW * DD * 2);     // Wq|Wk|Wv|Wg|small(128)
  uint16_t* wob  = (uint16_t*)alloc((size_t)DD * DD * 2);
  uint16_t* qkvg = (uint16_t*)alloc((size_t)MTOK * NQ * 2);   // blocked layout
  float*    sc   = (float*)alloc((size_t)3 * BB * HH * TT * 4);
  float*    Lst  = (float*)alloc((size_t)BH * NC * 2 * 64 * 4);
  float4*   Pm   = (float4*)alloc((size_t)BH * NC * 16);
  uint16_t* ogb  = xb;

  // prep: all casts (weights, x, small-proj weight block) in one dispatch
  prep_kernel<<<9344, 256, 0, stream>>>(
      x, Wq, Wk, Wv, Wg, Wo, Wb, Wfd, Wsd, wcat, wob, xb);

  // unified dispatch: 64 small-proj blocks (y<2, dispatched first) + qkvg GEMM
  // [8192,1024] @ [4096,1024]^T -> blocked bf16 (main IDs shifted by 64 == 0 mod 8)
  dim3 gq(NQ / 128, MTOK / 128 + 2);
  gemm128<0><<<gq, 256, 0, stream>>>(xb, wcat, qkvg, nullptr, bfd, bsd, sc, NQ, DD);

  // chunked scan: partA (local) then partC (lookback + replay)
  dim3 gs(NC, BH);
  scan_partA<<<gs, 64, 0, stream>>>(qkvg, sc, Lst, Pm);
  scan_partC<<<gs, 64, 0, stream>>>(qkvg, sc, Lst, Pm, ogb);

  // out = (o*g) @ Wo^T, fp32 row-major out (2D grid, 8%8==0 aligned)
  dim3 go(DD / 128, MTOK / 128);
  gemm128<1><<<go, 256, 0, stream>>>(ogb, wob, nullptr, out, bfd, bsd, nullptr, DD, DD);
}

// Round 13
// 170.765 us; speedup vs baseline: 1.0427x; 1.0427x over previous
//
#include <hip/hip_runtime.h>
#include <hip/hip_bf16.h>
#include <stdint.h>

#define BB 4
#define TT 2048
#define DD 1024
#define HH 16
#define MTOK (BB*TT)
#define NQ 4096            // q|k|v|g concat width
#define NW (NQ+128)        // wcat rows incl. small-proj block
#define TC 32              // scan chunk length
#define NC (TT/TC)         // 64 chunks
#define BH (BB*HH)         // 64
#define ROWT (16*NQ)       // elements per 16-row blocked stripe

typedef __bf16 bf16x8 __attribute__((ext_vector_type(8)));
typedef float f32x4 __attribute__((ext_vector_type(4)));

__device__ __forceinline__ uint16_t f2bf(float f){
  uint32_t u = __float_as_uint(f);
  u += 0x7fffu + ((u >> 16) & 1u);
  return (uint16_t)(u >> 16);
}
__device__ __forceinline__ float bf2f(uint32_t h){ return __uint_as_float(h << 16); }
// sigmoid via fast exp + raw v_rcp_f32 (1 ulp) -- avoids precise-div expansion
__device__ __forceinline__ float sigm(float z){
  return __builtin_amdgcn_rcpf(1.f + __expf(-z));
}

__device__ __forceinline__ void gll16(const uint16_t* src, uint16_t* dst){
  __builtin_amdgcn_global_load_lds(
      (const __attribute__((address_space(1))) void*)src,
      (__attribute__((address_space(3))) void*)dst, 16, 0, 0);
}
// extract bf16 element e (static) from a uint4 (8 bf16)
__device__ __forceinline__ float bfel(const uint4& v, int e){
  uint32_t wrd = ((e>>1)==0) ? v.x : ((e>>1)==1) ? v.y : ((e>>1)==2) ? v.z : v.w;
  return bf2f((e&1) ? (wrd >> 16) : (wrd & 0xffffu));
}

// ---------------- prep: pure casts ----------------
// blocks [0,5120): Wq|Wk|Wv|Wg -> wcat rows 0..4095, Wo -> wob  (1 float4/thr)
// blocks [5120,9216): x -> xb  (2 float4/thr)
// blocks [9216,9344): Wb|Wfd|Wsd|zeros -> wcat rows 4096..4223  (4 elems/thr)
__global__ __launch_bounds__(256) void prep_kernel(
    const float* __restrict__ x,
    const float* __restrict__ Wq, const float* __restrict__ Wk,
    const float* __restrict__ Wv, const float* __restrict__ Wg,
    const float* __restrict__ Wo,
    const float* __restrict__ Wb, const float* __restrict__ Wfd,
    const float* __restrict__ Wsd,
    uint16_t* __restrict__ wcat, uint16_t* __restrict__ wob,
    uint16_t* __restrict__ xb)
{
  const int bx = blockIdx.x;
  if (bx < 5120){
    int i = bx * 256 + threadIdx.x;      // float4 index; 262144 per weight
    int wsel = i >> 18;
    int loc = i & 262143;
    const float* src = (wsel == 0) ? Wq : (wsel == 1) ? Wk : (wsel == 2) ? Wv : (wsel == 3) ? Wg : Wo;
    uint16_t* dst = (wsel < 4) ? (wcat + (size_t)wsel * DD * DD) : wob;
    float4 v = ((const float4*)src)[loc];
    ushort4 o;
    o.x = f2bf(v.x); o.y = f2bf(v.y); o.z = f2bf(v.z); o.w = f2bf(v.w);
    ((ushort4*)dst)[loc] = o;
  } else if (bx < 9216){
    int base = (bx - 5120) * 512 + threadIdx.x;
    #pragma unroll
    for (int rep = 0; rep < 2; rep++){
      int loc = base + rep * 256;
      float4 v = ((const float4*)x)[loc];
      ushort4 o;
      o.x = f2bf(v.x); o.y = f2bf(v.y); o.z = f2bf(v.z); o.w = f2bf(v.w);
      ((ushort4*)xb)[loc] = o;
    }
  } else {
    int u = (bx - 9216) * 256 + threadIdx.x;   // 4-elem unit; 256 units/row
    int row = u >> 8;
    int cidx = (u & 255) * 4;
    ushort4 o = {0, 0, 0, 0};
    if (row < 48){
      const float* src = (row < 16) ? (Wb + (size_t)row * DD)
                       : (row < 32) ? (Wfd + (size_t)(row - 16) * DD)
                                    : (Wsd + (size_t)(row - 32) * DD);
      float4 v = *(const float4*)(src + cidx);
      o.x = f2bf(v.x); o.y = f2bf(v.y); o.z = f2bf(v.z); o.w = f2bf(v.w);
    }
    *(ushort4*)(wcat + (size_t)(NQ + row) * DD + cidx) = o;
  }
}

// =============== 128x128 GEMM, BK=64, m97 2-barrier structure (R11-exact) ===============
// X:[M][K], W:[N][K] bf16 row-major. 256 thr = 4 waves (2x2), 64x64 per wave.
// 2D grid (x = n-tile, y = m-tile); x-width a multiple of 8 keeps XCD alignment.
// LDS 2x16KB single-buffered. Per-8-row XOR swizzle on 16B chunks:
// LDS chunk p holds logical (row=p>>3, quarter=(p&7)^(row&7)); inverse applied
// to the global source of global_load_lds (rule #21) -> 0 bank conflicts.
// MODE 0: qkvg blocked bf16 out (silu n0<3072, else sigmoid).
// MODE 1: plain f32 row-major out, no activation.
// MODE 2: small-proj (grid x=1, W = wcat rows 4096..): sigm(v+bias) -> sc f32
//         [3][B][H][T]. wc==1 waves and ni==3 compute discarded cols -> their
//         MFMAs are skipped (block-uniform per wave; barriers/staging intact).
// NOTE: each MODE is a separate kernel symbol -- MODE 2's extra registers must
// NOT perturb MODE 0's allocation (R12 lesson: merging cost 6->5 waves/SIMD).
template<int MODE>
__global__ __launch_bounds__(256) void gemm128(
    const uint16_t* __restrict__ X, const uint16_t* __restrict__ W,
    uint16_t* __restrict__ Y, float* __restrict__ Yf,
    const float* __restrict__ bfd, const float* __restrict__ bsd,
    float* __restrict__ scp, int N, int K)
{
  __shared__ __align__(16) uint16_t lA[128 * 64];
  __shared__ __align__(16) uint16_t lB[128 * 64];
  const int tid = threadIdx.x;
  const int m0 = blockIdx.y * 128, n0 = blockIdx.x * 128;
  const int l = tid & 63, w = tid >> 6;
  const int wr = w >> 1, wc = w & 1;
  const int g = l >> 4, r16 = l & 15;

  // staging: chunk p = n*256 + tid; row = p>>3, logical quarter = (p&7)^(row&7)
  const uint16_t* srcA[4];
  const uint16_t* srcB[4];
  uint16_t* dstA[4];
  uint16_t* dstB[4];
  #pragma unroll
  for (int n = 0; n < 4; n++){
    int p = n * 256 + tid;
    int row = p >> 3;
    int cq = (p & 7) ^ (row & 7);
    srcA[n] = X + (size_t)(m0 + row) * K + cq * 8;
    srcB[n] = W + (size_t)(n0 + row) * K + cq * 8;
    int basechunk = n * 256 + (tid & ~63);     // wave-uniform
    dstA[n] = lA + basechunk * 8;
    dstB[n] = lB + basechunk * 8;
  }

  // frag read offsets (u16 idx): row*64 + ((ks*4+g)^(row&7))*8
  int roA[4][2], roB[4][2];
  #pragma unroll
  for (int i = 0; i < 4; i++)
    #pragma unroll
    for (int ks = 0; ks < 2; ks++){
      roA[i][ks] = (wr * 64 + i * 16 + r16) * 64 + ((ks * 4 + g) ^ (r16 & 7)) * 8;
      roB[i][ks] = (wc * 64 + i * 16 + r16) * 64 + ((ks * 4 + g) ^ (r16 & 7)) * 8;
    }

  // MODE 2: only wc==0's ni=0..2 produce live columns (0..47)
  const bool doMfma = (MODE != 2) || (wc == 0);
  const int nLim = (MODE == 2) ? 3 : 4;

  f32x4 acc[4][4];
  #pragma unroll
  for (int i = 0; i < 4; i++)
    #pragma unroll
    for (int j = 0; j < 4; j++) acc[i][j] = (f32x4){0.f, 0.f, 0.f, 0.f};

  for (int kt = 0; kt < K; kt += 64){
    __syncthreads();                    // WAR: prior tile reads done
    #pragma unroll
    for (int n = 0; n < 4; n++){
      gll16(srcA[n] + kt, dstA[n]);
      gll16(srcB[n] + kt, dstB[n]);
    }
    __syncthreads();                    // compiler drains vmcnt(0) before barrier

    if (doMfma){
      #pragma unroll
      for (int ks = 0; ks < 2; ks++){
        bf16x8 af[4], bw[4];
        #pragma unroll
        for (int mi = 0; mi < 4; mi++) af[mi] = *(const bf16x8*)(lA + roA[mi][ks]);
        #pragma unroll
        for (int ni = 0; ni < nLim; ni++) bw[ni] = *(const bf16x8*)(lB + roB[ni][ks]);
        #pragma unroll
        for (int mi = 0; mi < 4; mi++)
          #pragma unroll
          for (int ni = 0; ni < nLim; ni++)
            acc[mi][ni] = __builtin_amdgcn_mfma_f32_16x16x32_bf16(af[mi], bw[ni], acc[mi][ni], 0, 0, 0);
      }
    }
  }

  // C/D layout: col=lane&15, row=(lane>>4)*4+reg  [m89-verified]
  if (MODE == 0){
    const bool dosig = (n0 >= 3 * DD);
    #pragma unroll
    for (int mi = 0; mi < 4; mi++){
      const int R0 = m0 + wr * 64 + mi * 16;
      const size_t rbase = (size_t)(R0 >> 4) * ROWT;
      #pragma unroll
      for (int ni = 0; ni < 4; ni++){
        const int C0 = n0 + wc * 64 + ni * 16;
        f32x4 v = acc[mi][ni];
        float o[4];
        #pragma unroll
        for (int r = 0; r < 4; r++){
          float xx = v[r];
          o[r] = dosig ? sigm(xx) : xx * sigm(xx);
        }
        uint2 pk;
        pk.x = (uint32_t)f2bf(o[0]) | ((uint32_t)f2bf(o[1]) << 16);
        pk.y = (uint32_t)f2bf(o[2]) | ((uint32_t)f2bf(o[3]) << 16);
        size_t off = rbase + (size_t)(C0 >> 4) * 256 + (size_t)r16 * 16 + g * 4;
        *(uint2*)(Y + off) = pk;
      }
    }
  } else if (MODE == 1){
    #pragma unroll
    for (int mi = 0; mi < 4; mi++){
      #pragma unroll
      for (int ni = 0; ni < 4; ni++){
        int rg = m0 + wr * 64 + mi * 16 + g * 4;
        int cg = n0 + wc * 64 + ni * 16 + r16;
        #pragma unroll
        for (int r = 0; r < 4; r++)
          Yf[(size_t)(rg + r) * N + cg] = acc[mi][ni][r];
      }
    }
  } else {
    // small-proj: cols 0..47 -> sc[grp][b][h][t] (f32); only wc==0 waves live
    if (wc == 0){
      #pragma unroll
      for (int ni = 0; ni < 3; ni++){
        const int grp = ni;                         // cols ni*16..+15
        const int h = r16;
        const float bias = (grp == 0) ? 0.f : (grp == 1) ? bfd[h] : bsd[h];
        #pragma unroll
        for (int mi = 0; mi < 4; mi++){
          const int R0 = m0 + wr * 64 + mi * 16 + g * 4;  // token rows R0..R0+3
          const int b = R0 >> 11, t = R0 & (TT - 1);
          f32x4 v = acc[mi][ni];
          float4 o;
          o.x = sigm(v[0] + bias);
          o.y = sigm(v[1] + bias);
          o.z = sigm(v[2] + bias);
          o.w = sigm(v[3] + bias);
          *(float4*)(scp + (((size_t)grp * BB + b) * HH + h) * TT + t) = o;
        }
      }
    }
  }
}

// ---------------- chunked scan over blocked qkvg ----------------
// blocked elem(R,C) = (R>>4)*ROWT + (C>>4)*256 + (C&15)*16 + (R&15)
// step: [sf,ss]' = M_t [sf,ss] + 1.05*u_t*[1,1],  M_t = [[f,.05s],[.05f,s]]

// Pass A: per (chunk j, bh): zero-entry local end state L + chunk 2x2 matrix P
__global__ __launch_bounds__(64) void scan_partA(
    const uint16_t* __restrict__ qkvg, const float* __restrict__ sc,
    float* __restrict__ Lst, float4* __restrict__ Pm)
{
  int j = blockIdx.x, bh = blockIdx.y;
  int b = bh >> 4, h = bh & 15;
  int c = threadIdx.x;
  const int ci = c & 15;
  const size_t tc_k = (size_t)((DD     + h * 64 + c) >> 4) * 256 + ci * 16;
  const size_t tc_v = (size_t)((2 * DD + h * 64 + c) >> 4) * 256 + ci * 16;
  const float* bet = sc + ((size_t)(0 * BB + b) * HH + h) * TT + j * TC;
  const float* fdp = sc + ((size_t)(1 * BB + b) * HH + h) * TT + j * TC;
  const float* sdp = sc + ((size_t)(2 * BB + b) * HH + h) * TT + j * TC;

  float sf = 0.f, ss = 0.f;
  float p00 = 1.f, p01 = 0.f, p10 = 0.f, p11 = 1.f;
  #pragma unroll
  for (int t16 = 0; t16 < 2; ++t16){
    int R0 = b * TT + j * TC + t16 * 16;
    size_t tb = (size_t)(R0 >> 4) * ROWT;
    uint4 kl = *(const uint4*)(qkvg + tb + tc_k);
    uint4 kh = *(const uint4*)(qkvg + tb + tc_k + 8);
    uint4 vl = *(const uint4*)(qkvg + tb + tc_v);
    uint4 vh = *(const uint4*)(qkvg + tb + tc_v + 8);
    const float* bt = bet + t16 * 16;
    const float* ft = fdp + t16 * 16;
    const float* st = sdp + t16 * 16;
    #pragma unroll
    for (int u = 0; u < 16; ++u){
      float kv = (u < 8) ? bfel(kl, u) : bfel(kh, u - 8);
      float vv = (u < 8) ? bfel(vl, u) : bfel(vh, u - 8);
      float btv = bt[u], f = ft[u], s = st[u];
      float uu = 1.05f * btv * kv * vv;
      float bq = 0.05f * s, cq = 0.05f * f;
      float nf = f * sf + bq * ss + uu;
      float ns = cq * sf + s * ss + uu;
      sf = nf; ss = ns;
      float q00 = f * p00 + bq * p10, q01 = f * p01 + bq * p11;
      float q10 = cq * p00 + s * p10, q11 = cq * p01 + s * p11;
      p00 = q00; p01 = q01; p10 = q10; p11 = q11;
    }
  }
  size_t base = ((size_t)bh * NC + j) * 2;
  Lst[(base + 0) * 64 + c] = sf;
  Lst[(base + 1) * 64 + c] = ss;
  if (c == 0) Pm[(size_t)bh * NC + j] = make_float4(p00, p01, p10, p11);
}

// Pass C (with folded lookback): compute entry state E_j from Lst/Pm (all
// written by partA, complete at kernel boundary -- deterministic, no atomics),
// then replay chunk and write og row-major via LDS micro-transpose.
__global__ __launch_bounds__(64) void scan_partC(
    const uint16_t* __restrict__ qkvg, const float* __restrict__ sc,
    const float* __restrict__ Lst, const float4* __restrict__ Pm,
    uint16_t* __restrict__ og)
{
  __shared__ uint16_t ot[16 * 64];
  int j = blockIdx.x, bh = blockIdx.y;
  int b = bh >> 4, h = bh & 15;
  int c = threadIdx.x;
  const int ci = c & 15;

  // forward lookback: E = P_i * E + L_i for i = 0..j-1
  float sf = 0.f, ss = 0.f;
  for (int i = 0; i < j; ++i){
    size_t pbase = ((size_t)bh * NC + i) * 2;
    float lf = Lst[(pbase + 0) * 64 + c];
    float ls = Lst[(pbase + 1) * 64 + c];
    float4 P = Pm[(size_t)bh * NC + i];
    float nf = P.x * sf + P.y * ss + lf;
    float ns = P.z * sf + P.w * ss + ls;
    sf = nf; ss = ns;
  }

  const size_t tc_q = (size_t)((         h * 64 + c) >> 4) * 256 + ci * 16;
  const size_t tc_k = (size_t)((DD     + h * 64 + c) >> 4) * 256 + ci * 16;
  const size_t tc_v = (size_t)((2 * DD + h * 64 + c) >> 4) * 256 + ci * 16;
  const size_t tc_g = (size_t)((3 * DD + h * 64 + c) >> 4) * 256 + ci * 16;
  const float* bet = sc + ((size_t)(0 * BB + b) * HH + h) * TT + j * TC;
  const float* fdp = sc + ((size_t)(1 * BB + b) * HH + h) * TT + j * TC;
  const float* sdp = sc + ((size_t)(2 * BB + b) * HH + h) * TT + j * TC;

  #pragma unroll
  for (int t16 = 0; t16 < 2; ++t16){
    int R0 = b * TT + j * TC + t16 * 16;
    size_t tb = (size_t)(R0 >> 4) * ROWT;
    uint4 ql = *(const uint4*)(qkvg + tb + tc_q);
    uint4 qh = *(const uint4*)(qkvg + tb + tc_q + 8);
    uint4 kl = *(const uint4*)(qkvg + tb + tc_k);
    uint4 kh = *(const uint4*)(qkvg + tb + tc_k + 8);
    uint4 vl = *(const uint4*)(qkvg + tb + tc_v);
    uint4 vh = *(const uint4*)(qkvg + tb + tc_v + 8);
    uint4 gl = *(const uint4*)(qkvg + tb + tc_g);
    uint4 gh = *(const uint4*)(qkvg + tb + tc_g + 8);
    const float* bt = bet + t16 * 16;
    const float* ft = fdp + t16 * 16;
    const float* st = sdp + t16 * 16;
    #pragma unroll
    for (int u = 0; u < 16; ++u){
      float qv = (u < 8) ? bfel(ql, u) : bfel(qh, u - 8);
      float kv = (u < 8) ? bfel(kl, u) : bfel(kh, u - 8);
      float vv = (u < 8) ? bfel(vl, u) : bfel(vh, u - 8);
      float gv = (u < 8) ? bfel(gl, u) : bfel(gh, u - 8);
      float btv = bt[u], f = ft[u], s = st[u];
      sf *= f; ss *= s;
      float o = 0.5f * qv * (sf + ss);
      float uu = btv * kv * vv;
      sf += uu; ss += uu;
      float nf = sf + 0.05f * ss, ns = ss + 0.05f * sf;
      sf = nf; ss = ns;
      ot[u * 64 + c] = f2bf(o * gv);
    }
    __syncthreads();
    {
      int u0 = c >> 3, c8 = c & 7;
      uint4 d0 = *(const uint4*)&ot[u0 * 64 + c8 * 8];
      uint4 d1 = *(const uint4*)&ot[(u0 + 8) * 64 + c8 * 8];
      uint16_t* ob = og + (size_t)R0 * DD + h * 64 + c8 * 8;
      *(uint4*)(ob + (size_t)u0 * DD) = d0;
      *(uint4*)(ob + (size_t)(u0 + 8) * DD) = d1;
    }
    __syncthreads();
  }
}

extern "C" void kernel_launch(void* const* d_in, const int* in_sizes, int n_in,
                              void* d_out, int out_size, void* d_ws, size_t ws_size,
                              hipStream_t stream)
{
  const float* x   = (const float*)d_in[0];
  const float* Wq  = (const float*)d_in[1];
  const float* Wk  = (const float*)d_in[2];
  const float* Wv  = (const float*)d_in[3];
  const float* Wo  = (const float*)d_in[4];
  const float* Wb  = (const float*)d_in[5];
  const float* Wfd = (const float*)d_in[6];
  const float* bfd = (const float*)d_in[7];
  const float* Wsd = (const float*)d_in[8];
  const float* bsd = (const float*)d_in[9];
  const float* Wg  = (const float*)d_in[10];
  float* out = (float*)d_out;

  char* ws = (char*)d_ws;
  size_t off = 0;
  auto alloc = [&](size_t bytes) -> void* {
    void* p = ws + off;
    off += (bytes + 255) & ~(size_t)255;
    return p;
  };

  uint16_t* xb   = (uint16_t*)alloc((size_t)MTOK * DD * 2);   // doubles as ogb later
  uint16_t* wcat = (uint16_t*)alloc((size_t)NW * DD * 2);     // Wq|Wk|Wv|Wg|small(128)
  uint16_t* wob  = (uint16_t*)alloc((size_t)DD * DD * 2);
  uint16_t* qkvg = (uint16_t*)alloc((size_t)MTOK * NQ * 2);   // blocked layout
  float*    sc   = (float*)alloc((size_t)3 * BB * HH * TT * 4);
  float*    Lst  = (float*)alloc((size_t)BH * NC * 2 * 64 * 4);
  float4*   Pm   = (float4*)alloc((size_t)BH * NC * 16);
  uint16_t* ogb  = xb;

  // prep: all casts (weights, x, small-proj weight block) in one dispatch
  prep_kernel<<<9344, 256, 0, stream>>>(
      x, Wq, Wk, Wv, Wg, Wo, Wb, Wfd, Wsd, wcat, wob, xb);

  // small projections: [8192,1024] @ [128,1024]^T -> sc (f32), tiny MFMA GEMM
  dim3 gp(1, MTOK / 128);
  gemm128<2><<<gp, 256, 0, stream>>>(xb, wcat + (size_t)NQ * DD, nullptr, nullptr,
                                     bfd, bsd, sc, NQ, DD);

  // fused q|k|v|g GEMM: [8192,1024] @ [4096,1024]^T -> blocked bf16 (R11-exact 2D grid)
  dim3 gq(NQ / 128, MTOK / 128);
  gemm128<0><<<gq, 256, 0, stream>>>(xb, wcat, qkvg, nullptr, bfd, bsd, nullptr, NQ, DD);

  // chunked scan: partA (local) then partC (lookback + replay)
  dim3 gs(NC, BH);
  scan_partA<<<gs, 64, 0, stream>>>(qkvg, sc, Lst, Pm);
  scan_partC<<<gs, 64, 0, stream>>>(qkvg, sc, Lst, Pm, ogb);

  // out = (o*g) @ Wo^T, fp32 row-major out (2D grid, 8%8==0 aligned)
  dim3 go(DD / 128, MTOK / 128);
  gemm128<1><<<go, 256, 0, stream>>>(ogb, wob, nullptr, out, bfd, bsd, nullptr, DD, DD);
}

// Round 14
// 163.077 us; speedup vs baseline: 1.0918x; 1.0471x over previous
//
#include <hip/hip_runtime.h>
#include <hip/hip_bf16.h>
#include <stdint.h>

#define BB 4
#define TT 2048
#define DD 1024
#define HH 16
#define MTOK (BB*TT)
#define NQ 4096            // q|k|v|g concat width
#define NW (NQ+128)        // wcat rows incl. small-proj block
#define TC 32              // scan chunk length
#define NC (TT/TC)         // 64 chunks
#define BH (BB*HH)         // 64
#define ROWT (16*NQ)       // elements per 16-row blocked stripe

typedef __bf16 bf16x8 __attribute__((ext_vector_type(8)));
typedef float f32x4 __attribute__((ext_vector_type(4)));

__device__ __forceinline__ uint16_t f2bf(float f){
  uint32_t u = __float_as_uint(f);
  u += 0x7fffu + ((u >> 16) & 1u);
  return (uint16_t)(u >> 16);
}
__device__ __forceinline__ float bf2f(uint32_t h){ return __uint_as_float(h << 16); }
// sigmoid via fast exp + raw v_rcp_f32 (1 ulp) -- avoids precise-div expansion
__device__ __forceinline__ float sigm(float z){
  return __builtin_amdgcn_rcpf(1.f + __expf(-z));
}

__device__ __forceinline__ void gll16(const uint16_t* src, uint16_t* dst){
  __builtin_amdgcn_global_load_lds(
      (const __attribute__((address_space(1))) void*)src,
      (__attribute__((address_space(3))) void*)dst, 16, 0, 0);
}
// extract bf16 element e (static) from a uint4 (8 bf16)
__device__ __forceinline__ float bfel(const uint4& v, int e){
  uint32_t wrd = ((e>>1)==0) ? v.x : ((e>>1)==1) ? v.y : ((e>>1)==2) ? v.z : v.w;
  return bf2f((e&1) ? (wrd >> 16) : (wrd & 0xffffu));
}

// ---------------- prep: pure casts (R13-exact) ----------------
__global__ __launch_bounds__(256) void prep_kernel(
    const float* __restrict__ x,
    const float* __restrict__ Wq, const float* __restrict__ Wk,
    const float* __restrict__ Wv, const float* __restrict__ Wg,
    const float* __restrict__ Wo,
    const float* __restrict__ Wb, const float* __restrict__ Wfd,
    const float* __restrict__ Wsd,
    uint16_t* __restrict__ wcat, uint16_t* __restrict__ wob,
    uint16_t* __restrict__ xb)
{
  const int bx = blockIdx.x;
  if (bx < 5120){
    int i = bx * 256 + threadIdx.x;      // float4 index; 262144 per weight
    int wsel = i >> 18;
    int loc = i & 262143;
    const float* src = (wsel == 0) ? Wq : (wsel == 1) ? Wk : (wsel == 2) ? Wv : (wsel == 3) ? Wg : Wo;
    uint16_t* dst = (wsel < 4) ? (wcat + (size_t)wsel * DD * DD) : wob;
    float4 v = ((const float4*)src)[loc];
    ushort4 o;
    o.x = f2bf(v.x); o.y = f2bf(v.y); o.z = f2bf(v.z); o.w = f2bf(v.w);
    ((ushort4*)dst)[loc] = o;
  } else if (bx < 9216){
    int base = (bx - 5120) * 512 + threadIdx.x;
    #pragma unroll
    for (int rep = 0; rep < 2; rep++){
      int loc = base + rep * 256;
      float4 v = ((const float4*)x)[loc];
      ushort4 o;
      o.x = f2bf(v.x); o.y = f2bf(v.y); o.z = f2bf(v.z); o.w = f2bf(v.w);
      ((ushort4*)xb)[loc] = o;
    }
  } else {
    int u = (bx - 9216) * 256 + threadIdx.x;   // 4-elem unit; 256 units/row
    int row = u >> 8;
    int cidx = (u & 255) * 4;
    ushort4 o = {0, 0, 0, 0};
    if (row < 48){
      const float* src = (row < 16) ? (Wb + (size_t)row * DD)
                       : (row < 32) ? (Wfd + (size_t)(row - 16) * DD)
                                    : (Wsd + (size_t)(row - 32) * DD);
      float4 v = *(const float4*)(src + cidx);
      o.x = f2bf(v.x); o.y = f2bf(v.y); o.z = f2bf(v.z); o.w = f2bf(v.w);
    }
    *(ushort4*)(wcat + (size_t)(NQ + row) * DD + cidx) = o;
  }
}

// =============== 256x256 8-phase GEMM for qkvg (m201 template port) ===============
// X:[8192][1024], W:[4096][1024] bf16 row-major. 512 thr = 8 waves (2M x 4N),
// per-wave 128x64 = acc[8][4]. K-step 64, NT=16. LDS = 2dbuf x 2 K-HALVES x
// [256 rows][32 kcols] x (A,B) = 128 KiB. K-split halves are the enabler:
// A0/B0[t] die after ph1 -> staggered 1-unit-per-phase prefetch into buf^1
// with COUNTED vmcnt(4) twice per K-step (never 0 in steady state).
//   ph0: ds a[0-7]+b0,b1 (half0) | stage A0[t+1] | bar,lgkm0,prio: 16 MFMA
//   ph1: ds b2,b3 (half0)        | stage B0[t+1] | ... 16 MFMA | vmcnt(4)
//   ph2: ds a[0-7]+b0,b1 (half1) | stage A1[t+1] | ... 16 MFMA
//   ph3: ds b2,b3 (half1)        | stage B1[t+1] | ... 16 MFMA | vmcnt(4)
// Raw s_barrier only (__syncthreads would drain vmcnt(0) -> kills the scheme).
// Quarter swizzle physQ = q ^ ((row>>1)&3), inverse on global source (rule 21).
// Epilogue: blocked bf16 out, silu n0<3072 else sigmoid.
__global__ __launch_bounds__(512, 2) void gemm256_qkvg(
    const uint16_t* __restrict__ X, const uint16_t* __restrict__ W,
    uint16_t* __restrict__ Y)
{
  constexpr int K = DD;
  constexpr int NT = K / 64;
  constexpr int HSZ = 8192;                       // u16 per [256][32] half
  __shared__ __align__(16) uint16_t sA[2][2][HSZ];
  __shared__ __align__(16) uint16_t sB[2][2][HSZ];

  const int tid = threadIdx.x;
  const int m0 = blockIdx.y * 256, n0 = blockIdx.x * 256;
  const int l = tid & 63, w = tid >> 6;
  const int wr = w >> 2, wc = w & 3;
  const int g = l >> 4, r16 = l & 15;

  // staging: chunk c (16B) of a half: row=c>>2, physQ=c&3, logQ=(c&3)^((c>>3)&3)
  const int c1 = tid + 512;
  const int r0 = tid >> 2, q0 = (tid & 3) ^ ((tid >> 3) & 3);
  const int r1 = c1 >> 2,  q1 = (c1 & 3) ^ ((c1 >> 3) & 3);
  const uint16_t* pA0 = X + (size_t)(m0 + r0) * K + q0 * 8;
  const uint16_t* pA1 = X + (size_t)(m0 + r1) * K + q1 * 8;
  const uint16_t* pB0 = W + (size_t)(n0 + r0) * K + q0 * 8;
  const uint16_t* pB1 = W + (size_t)(n0 + r1) * K + q1 * 8;
  const int d0 = w * 512, d1 = 4096 + w * 512;    // wave-uniform LDS u16 offs

  // frag read offsets within a half (u16): row*32 + (g^((r16>>1)&3))*8
  const int fsw = (g ^ ((r16 >> 1) & 3)) * 8;
  int roA[8], roB[4];
  #pragma unroll
  for (int mi = 0; mi < 8; mi++) roA[mi] = (wr * 128 + mi * 16 + r16) * 32 + fsw;
  #pragma unroll
  for (int ni = 0; ni < 4; ni++) roB[ni] = (wc * 64 + ni * 16 + r16) * 32 + fsw;

  f32x4 acc[8][4];
  #pragma unroll
  for (int i = 0; i < 8; i++)
    #pragma unroll
    for (int j = 0; j < 4; j++) acc[i][j] = (f32x4){0.f, 0.f, 0.f, 0.f};

  // prologue: stage tile0's 4 units (A0,B0,A1,B1); A0,B0 resident, A1,B1 in flight
  gll16(pA0,      &sA[0][0][d0]); gll16(pA1,      &sA[0][0][d1]);
  gll16(pB0,      &sB[0][0][d0]); gll16(pB1,      &sB[0][0][d1]);
  gll16(pA0 + 32, &sA[0][1][d0]); gll16(pA1 + 32, &sA[0][1][d1]);
  gll16(pB0 + 32, &sB[0][1][d0]); gll16(pB1 + 32, &sB[0][1][d1]);
  asm volatile("s_waitcnt vmcnt(4)" ::: "memory");
  __builtin_amdgcn_sched_barrier(0);
  __builtin_amdgcn_s_barrier();

  #pragma unroll 1
  for (int t = 0; t < NT; ++t){
    const int buf = t & 1, nb = buf ^ 1;
    const bool st = (t + 1 < NT);
    const int kof = (t + 1) * 64;
    bf16x8 a[8], b0, b1, b2, b3;

    // ---- ph0: half0 A frags + B[0,1]; stage A0[t+1] ----
    #pragma unroll
    for (int mi = 0; mi < 8; mi++) a[mi] = *(const bf16x8*)&sA[buf][0][roA[mi]];
    b0 = *(const bf16x8*)&sB[buf][0][roB[0]];
    b1 = *(const bf16x8*)&sB[buf][0][roB[1]];
    if (st){ gll16(pA0 + kof, &sA[nb][0][d0]); gll16(pA1 + kof, &sA[nb][0][d1]); }
    __builtin_amdgcn_s_barrier();
    asm volatile("s_waitcnt lgkmcnt(0)" ::: "memory");
    __builtin_amdgcn_sched_barrier(0);
    __builtin_amdgcn_s_setprio(1);
    #pragma unroll
    for (int mi = 0; mi < 8; mi++){
      acc[mi][0] = __builtin_amdgcn_mfma_f32_16x16x32_bf16(a[mi], b0, acc[mi][0], 0, 0, 0);
      acc[mi][1] = __builtin_amdgcn_mfma_f32_16x16x32_bf16(a[mi], b1, acc[mi][1], 0, 0, 0);
    }
    __builtin_amdgcn_s_setprio(0);
    __builtin_amdgcn_s_barrier();

    // ---- ph1: half0 B[2,3]; stage B0[t+1]; counted vmcnt ----
    b2 = *(const bf16x8*)&sB[buf][0][roB[2]];
    b3 = *(const bf16x8*)&sB[buf][0][roB[3]];
    if (st){ gll16(pB0 + kof, &sB[nb][0][d0]); gll16(pB1 + kof, &sB[nb][0][d1]); }
    __builtin_amdgcn_s_barrier();
    asm volatile("s_waitcnt lgkmcnt(0)" ::: "memory");
    __builtin_amdgcn_sched_barrier(0);
    __builtin_amdgcn_s_setprio(1);
    #pragma unroll
    for (int mi = 0; mi < 8; mi++){
      acc[mi][2] = __builtin_amdgcn_mfma_f32_16x16x32_bf16(a[mi], b2, acc[mi][2], 0, 0, 0);
      acc[mi][3] = __builtin_amdgcn_mfma_f32_16x16x32_bf16(a[mi], b3, acc[mi][3], 0, 0, 0);
    }
    __builtin_amdgcn_s_setprio(0);
    if (st) asm volatile("s_waitcnt vmcnt(4)" ::: "memory");   // A1,B1[t] resident
    else    asm volatile("s_waitcnt vmcnt(0)" ::: "memory");   // tail drain
    __builtin_amdgcn_sched_barrier(0);
    __builtin_amdgcn_s_barrier();

    // ---- ph2: half1 A frags + B[0,1]; stage A1[t+1] ----
    #pragma unroll
    for (int mi = 0; mi < 8; mi++) a[mi] = *(const bf16x8*)&sA[buf][1][roA[mi]];
    b0 = *(const bf16x8*)&sB[buf][1][roB[0]];
    b1 = *(const bf16x8*)&sB[buf][1][roB[1]];
    if (st){ gll16(pA0 + kof + 32, &sA[nb][1][d0]); gll16(pA1 + kof + 32, &sA[nb][1][d1]); }
    __builtin_amdgcn_s_barrier();
    asm volatile("s_waitcnt lgkmcnt(0)" ::: "memory");
    __builtin_amdgcn_sched_barrier(0);
    __builtin_amdgcn_s_setprio(1);
    #pragma unroll
    for (int mi = 0; mi < 8; mi++){
      acc[mi][0] = __builtin_amdgcn_mfma_f32_16x16x32_bf16(a[mi], b0, acc[mi][0], 0, 0, 0);
      acc[mi][1] = __builtin_amdgcn_mfma_f32_16x16x32_bf16(a[mi], b1, acc[mi][1], 0, 0, 0);
    }
    __builtin_amdgcn_s_setprio(0);
    __builtin_amdgcn_s_barrier();

    // ---- ph3: half1 B[2,3]; stage B1[t+1]; counted vmcnt ----
    b2 = *(const bf16x8*)&sB[buf][1][roB[2]];
    b3 = *(const bf16x8*)&sB[buf][1][roB[3]];
    if (st){ gll16(pB0 + kof + 32, &sB[nb][1][d0]); gll16(pB1 + kof + 32, &sB[nb][1][d1]); }
    __builtin_amdgcn_s_barrier();
    asm volatile("s_waitcnt lgkmcnt(0)" ::: "memory");
    __builtin_amdgcn_sched_barrier(0);
    __builtin_amdgcn_s_setprio(1);
    #pragma unroll
    for (int mi = 0; mi < 8; mi++){
      acc[mi][2] = __builtin_amdgcn_mfma_f32_16x16x32_bf16(a[mi], b2, acc[mi][2], 0, 0, 0);
      acc[mi][3] = __builtin_amdgcn_mfma_f32_16x16x32_bf16(a[mi], b3, acc[mi][3], 0, 0, 0);
    }
    __builtin_amdgcn_s_setprio(0);
    if (st){
      asm volatile("s_waitcnt vmcnt(4)" ::: "memory");         // A0,B0[t+1] resident
      __builtin_amdgcn_sched_barrier(0);
      __builtin_amdgcn_s_barrier();
    }
  }

  // epilogue: C/D col=lane&15, row=(lane>>4)*4+reg; blocked store, 8B/lane/frag
  const bool dosig = (n0 >= 3 * DD);
  #pragma unroll
  for (int mi = 0; mi < 8; ++mi){
    const int R0 = m0 + wr * 128 + mi * 16;
    const size_t rbase = (size_t)(R0 >> 4) * ROWT;
    #pragma unroll
    for (int ni = 0; ni < 4; ++ni){
      const int C0 = n0 + wc * 64 + ni * 16;
      f32x4 v = acc[mi][ni];
      float o[4];
      #pragma unroll
      for (int r = 0; r < 4; r++){
        float xx = v[r];
        o[r] = dosig ? sigm(xx) : xx * sigm(xx);
      }
      uint2 pk;
      pk.x = (uint32_t)f2bf(o[0]) | ((uint32_t)f2bf(o[1]) << 16);
      pk.y = (uint32_t)f2bf(o[2]) | ((uint32_t)f2bf(o[3]) << 16);
      size_t off = rbase + (size_t)(C0 >> 4) * 256 + (size_t)r16 * 16 + g * 4;
      *(uint2*)(Y + off) = pk;
    }
  }
}

// =============== 128x128 GEMM, BK=64, m97 2-barrier structure (R13-exact) ===============
// MODE 1: plain f32 row-major out. MODE 2: small-proj -> sc f32 [3][B][H][T].
template<int MODE>
__global__ __launch_bounds__(256) void gemm128(
    const uint16_t* __restrict__ X, const uint16_t* __restrict__ W,
    uint16_t* __restrict__ Y, float* __restrict__ Yf,
    const float* __restrict__ bfd, const float* __restrict__ bsd,
    float* __restrict__ scp, int N, int K)
{
  __shared__ __align__(16) uint16_t lA[128 * 64];
  __shared__ __align__(16) uint16_t lB[128 * 64];
  const int tid = threadIdx.x;
  const int m0 = blockIdx.y * 128, n0 = blockIdx.x * 128;
  const int l = tid & 63, w = tid >> 6;
  const int wr = w >> 1, wc = w & 1;
  const int g = l >> 4, r16 = l & 15;

  const uint16_t* srcA[4];
  const uint16_t* srcB[4];
  uint16_t* dstA[4];
  uint16_t* dstB[4];
  #pragma unroll
  for (int n = 0; n < 4; n++){
    int p = n * 256 + tid;
    int row = p >> 3;
    int cq = (p & 7) ^ (row & 7);
    srcA[n] = X + (size_t)(m0 + row) * K + cq * 8;
    srcB[n] = W + (size_t)(n0 + row) * K + cq * 8;
    int basechunk = n * 256 + (tid & ~63);
    dstA[n] = lA + basechunk * 8;
    dstB[n] = lB + basechunk * 8;
  }

  int roA[4][2], roB[4][2];
  #pragma unroll
  for (int i = 0; i < 4; i++)
    #pragma unroll
    for (int ks = 0; ks < 2; ks++){
      roA[i][ks] = (wr * 64 + i * 16 + r16) * 64 + ((ks * 4 + g) ^ (r16 & 7)) * 8;
      roB[i][ks] = (wc * 64 + i * 16 + r16) * 64 + ((ks * 4 + g) ^ (r16 & 7)) * 8;
    }

  const bool doMfma = (MODE != 2) || (wc == 0);
  const int nLim = (MODE == 2) ? 3 : 4;

  f32x4 acc[4][4];
  #pragma unroll
  for (int i = 0; i < 4; i++)
    #pragma unroll
    for (int j = 0; j < 4; j++) acc[i][j] = (f32x4){0.f, 0.f, 0.f, 0.f};

  for (int kt = 0; kt < K; kt += 64){
    __syncthreads();
    #pragma unroll
    for (int n = 0; n < 4; n++){
      gll16(srcA[n] + kt, dstA[n]);
      gll16(srcB[n] + kt, dstB[n]);
    }
    __syncthreads();

    if (doMfma){
      #pragma unroll
      for (int ks = 0; ks < 2; ks++){
        bf16x8 af[4], bw[4];
        #pragma unroll
        for (int mi = 0; mi < 4; mi++) af[mi] = *(const bf16x8*)(lA + roA[mi][ks]);
        #pragma unroll
        for (int ni = 0; ni < nLim; ni++) bw[ni] = *(const bf16x8*)(lB + roB[ni][ks]);
        #pragma unroll
        for (int mi = 0; mi < 4; mi++)
          #pragma unroll
          for (int ni = 0; ni < nLim; ni++)
            acc[mi][ni] = __builtin_amdgcn_mfma_f32_16x16x32_bf16(af[mi], bw[ni], acc[mi][ni], 0, 0, 0);
      }
    }
  }

  if (MODE == 1){
    #pragma unroll
    for (int mi = 0; mi < 4; mi++){
      #pragma unroll
      for (int ni = 0; ni < 4; ni++){
        int rg = m0 + wr * 64 + mi * 16 + g * 4;
        int cg = n0 + wc * 64 + ni * 16 + r16;
        #pragma unroll
        for (int r = 0; r < 4; r++)
          Yf[(size_t)(rg + r) * N + cg] = acc[mi][ni][r];
      }
    }
  } else {
    if (wc == 0){
      #pragma unroll
      for (int ni = 0; ni < 3; ni++){
        const int grp = ni;
        const int h = r16;
        const float bias = (grp == 0) ? 0.f : (grp == 1) ? bfd[h] : bsd[h];
        #pragma unroll
        for (int mi = 0; mi < 4; mi++){
          const int R0 = m0 + wr * 64 + mi * 16 + g * 4;
          const int b = R0 >> 11, t = R0 & (TT - 1);
          f32x4 v = acc[mi][ni];
          float4 o;
          o.x = sigm(v[0] + bias);
          o.y = sigm(v[1] + bias);
          o.z = sigm(v[2] + bias);
          o.w = sigm(v[3] + bias);
          *(float4*)(scp + (((size_t)grp * BB + b) * HH + h) * TT + t) = o;
        }
      }
    }
  }
}

// ---------------- chunked scan over blocked qkvg (R13-exact) ----------------
__global__ __launch_bounds__(64) void scan_partA(
    const uint16_t* __restrict__ qkvg, const float* __restrict__ sc,
    float* __restrict__ Lst, float4* __restrict__ Pm)
{
  int j = blockIdx.x, bh = blockIdx.y;
  int b = bh >> 4, h = bh & 15;
  int c = threadIdx.x;
  const int ci = c & 15;
  const size_t tc_k = (size_t)((DD     + h * 64 + c) >> 4) * 256 + ci * 16;
  const size_t tc_v = (size_t)((2 * DD + h * 64 + c) >> 4) * 256 + ci * 16;
  const float* bet = sc + ((size_t)(0 * BB + b) * HH + h) * TT + j * TC;
  const float* fdp = sc + ((size_t)(1 * BB + b) * HH + h) * TT + j * TC;
  const float* sdp = sc + ((size_t)(2 * BB + b) * HH + h) * TT + j * TC;

  float sf = 0.f, ss = 0.f;
  float p00 = 1.f, p01 = 0.f, p10 = 0.f, p11 = 1.f;
  #pragma unroll
  for (int t16 = 0; t16 < 2; ++t16){
    int R0 = b * TT + j * TC + t16 * 16;
    size_t tb = (size_t)(R0 >> 4) * ROWT;
    uint4 kl = *(const uint4*)(qkvg + tb + tc_k);
    uint4 kh = *(const uint4*)(qkvg + tb + tc_k + 8);
    uint4 vl = *(const uint4*)(qkvg + tb + tc_v);
    uint4 vh = *(const uint4*)(qkvg + tb + tc_v + 8);
    const float* bt = bet + t16 * 16;
    const float* ft = fdp + t16 * 16;
    const float* st = sdp + t16 * 16;
    #pragma unroll
    for (int u = 0; u < 16; ++u){
      float kv = (u < 8) ? bfel(kl, u) : bfel(kh, u - 8);
      float vv = (u < 8) ? bfel(vl, u) : bfel(vh, u - 8);
      float btv = bt[u], f = ft[u], s = st[u];
      float uu = 1.05f * btv * kv * vv;
      float bq = 0.05f * s, cq = 0.05f * f;
      float nf = f * sf + bq * ss + uu;
      float ns = cq * sf + s * ss + uu;
      sf = nf; ss = ns;
      float q00 = f * p00 + bq * p10, q01 = f * p01 + bq * p11;
      float q10 = cq * p00 + s * p10, q11 = cq * p01 + s * p11;
      p00 = q00; p01 = q01; p10 = q10; p11 = q11;
    }
  }
  size_t base = ((size_t)bh * NC + j) * 2;
  Lst[(base + 0) * 64 + c] = sf;
  Lst[(base + 1) * 64 + c] = ss;
  if (c == 0) Pm[(size_t)bh * NC + j] = make_float4(p00, p01, p10, p11);
}

__global__ __launch_bounds__(64) void scan_partC(
    const uint16_t* __restrict__ qkvg, const float* __restrict__ sc,
    const float* __restrict__ Lst, const float4* __restrict__ Pm,
    uint16_t* __restrict__ og)
{
  __shared__ uint16_t ot[16 * 64];
  int j = blockIdx.x, bh = blockIdx.y;
  int b = bh >> 4, h = bh & 15;
  int c = threadIdx.x;
  const int ci = c & 15;

  float sf = 0.f, ss = 0.f;
  for (int i = 0; i < j; ++i){
    size_t pbase = ((size_t)bh * NC + i) * 2;
    float lf = Lst[(pbase + 0) * 64 + c];
    float ls = Lst[(pbase + 1) * 64 + c];
    float4 P = Pm[(size_t)bh * NC + i];
    float nf = P.x * sf + P.y * ss + lf;
    float ns = P.z * sf + P.w * ss + ls;
    sf = nf; ss = ns;
  }

  const size_t tc_q = (size_t)((         h * 64 + c) >> 4) * 256 + ci * 16;
  const size_t tc_k = (size_t)((DD     + h * 64 + c) >> 4) * 256 + ci * 16;
  const size_t tc_v = (size_t)((2 * DD + h * 64 + c) >> 4) * 256 + ci * 16;
  const size_t tc_g = (size_t)((3 * DD + h * 64 + c) >> 4) * 256 + ci * 16;
  const float* bet = sc + ((size_t)(0 * BB + b) * HH + h) * TT + j * TC;
  const float* fdp = sc + ((size_t)(1 * BB + b) * HH + h) * TT + j * TC;
  const float* sdp = sc + ((size_t)(2 * BB + b) * HH + h) * TT + j * TC;

  #pragma unroll
  for (int t16 = 0; t16 < 2; ++t16){
    int R0 = b * TT + j * TC + t16 * 16;
    size_t tb = (size_t)(R0 >> 4) * ROWT;
    uint4 ql = *(const uint4*)(qkvg + tb + tc_q);
    uint4 qh = *(const uint4*)(qkvg + tb + tc_q + 8);
    uint4 kl = *(const uint4*)(qkvg + tb + tc_k);
    uint4 kh = *(const uint4*)(qkvg + tb + tc_k + 8);
    uint4 vl = *(const uint4*)(qkvg + tb + tc_v);
    uint4 vh = *(const uint4*)(qkvg + tb + tc_v + 8);
    uint4 gl = *(const uint4*)(qkvg + tb + tc_g);
    uint4 gh = *(const uint4*)(qkvg + tb + tc_g + 8);
    const float* bt = bet + t16 * 16;
    const float* ft = fdp + t16 * 16;
    const float* st = sdp + t16 * 16;
    #pragma unroll
    for (int u = 0; u < 16; ++u){
      float qv = (u < 8) ? bfel(ql, u) : bfel(qh, u - 8);
      float kv = (u < 8) ? bfel(kl, u) : bfel(kh, u - 8);
      float vv = (u < 8) ? bfel(vl, u) : bfel(vh, u - 8);
      float gv = (u < 8) ? bfel(gl, u) : bfel(gh, u - 8);
      float btv = bt[u], f = ft[u], s = st[u];
      sf *= f; ss *= s;
      float o = 0.5f * qv * (sf + ss);
      float uu = btv * kv * vv;
      sf += uu; ss += uu;
      float nf = sf + 0.05f * ss, ns = ss + 0.05f * sf;
      sf = nf; ss = ns;
      ot[u * 64 + c] = f2bf(o * gv);
    }
    __syncthreads();
    {
      int u0 = c >> 3, c8 = c & 7;
      uint4 d0 = *(const uint4*)&ot[u0 * 64 + c8 * 8];
      uint4 d1 = *(const uint4*)&ot[(u0 + 8) * 64 + c8 * 8];
      uint16_t* ob = og + (size_t)R0 * DD + h * 64 + c8 * 8;
      *(uint4*)(ob + (size_t)u0 * DD) = d0;
      *(uint4*)(ob + (size_t)(u0 + 8) * DD) = d1;
    }
    __syncthreads();
  }
}

extern "C" void kernel_launch(void* const* d_in, const int* in_sizes, int n_in,
                              void* d_out, int out_size, void* d_ws, size_t ws_size,
                              hipStream_t stream)
{
  const float* x   = (const float*)d_in[0];
  const float* Wq  = (const float*)d_in[1];
  const float* Wk  = (const float*)d_in[2];
  const float* Wv  = (const float*)d_in[3];
  const float* Wo  = (const float*)d_in[4];
  const float* Wb  = (const float*)d_in[5];
  const float* Wfd = (const float*)d_in[6];
  const float* bfd = (const float*)d_in[7];
  const float* Wsd = (const float*)d_in[8];
  const float* bsd = (const float*)d_in[9];
  const float* Wg  = (const float*)d_in[10];
  float* out = (float*)d_out;

  char* ws = (char*)d_ws;
  size_t off = 0;
  auto alloc = [&](size_t bytes) -> void* {
    void* p = ws + off;
    off += (bytes + 255) & ~(size_t)255;
    return p;
  };

  uint16_t* xb   = (uint16_t*)alloc((size_t)MTOK * DD * 2);   // doubles as ogb later
  uint16_t* wcat = (uint16_t*)alloc((size_t)NW * DD * 2);     // Wq|Wk|Wv|Wg|small(128)
  uint16_t* wob  = (uint16_t*)alloc((size_t)DD * DD * 2);
  uint16_t* qkvg = (uint16_t*)alloc((size_t)MTOK * NQ * 2);   // blocked layout
  float*    sc   = (float*)alloc((size_t)3 * BB * HH * TT * 4);
  float*    Lst  = (float*)alloc((size_t)BH * NC * 2 * 64 * 4);
  float4*   Pm   = (float4*)alloc((size_t)BH * NC * 16);
  uint16_t* ogb  = xb;

  // prep: all casts (weights, x, small-proj weight block) in one dispatch
  prep_kernel<<<9344, 256, 0, stream>>>(
      x, Wq, Wk, Wv, Wg, Wo, Wb, Wfd, Wsd, wcat, wob, xb);

  // small projections: [8192,1024] @ [128,1024]^T -> sc (f32), tiny MFMA GEMM
  dim3 gp(1, MTOK / 128);
  gemm128<2><<<gp, 256, 0, stream>>>(xb, wcat + (size_t)NQ * DD, nullptr, nullptr,
                                     bfd, bsd, sc, NQ, DD);

  // fused q|k|v|g GEMM: [8192,1024] @ [4096,1024]^T -> blocked bf16 (8-phase 256^2)
  dim3 gq(NQ / 256, MTOK / 256);
  gemm256_qkvg<<<gq, 512, 0, stream>>>(xb, wcat, qkvg);

  // chunked scan: partA (local) then partC (lookback + replay)
  dim3 gs(NC, BH);
  scan_partA<<<gs, 64, 0, stream>>>(qkvg, sc, Lst, Pm);
  scan_partC<<<gs, 64, 0, stream>>>(qkvg, sc, Lst, Pm, ogb);

  // out = (o*g) @ Wo^T, fp32 row-major out (2D grid, 8%8==0 aligned)
  dim3 go(DD / 128, MTOK / 128);
  gemm128<1><<<go, 256, 0, stream>>>(ogb, wob, nullptr, out, bfd, bsd, nullptr, DD, DD);
}

// Round 15
// 160.806 us; speedup vs baseline: 1.1073x; 1.0141x over previous
//
#include <hip/hip_runtime.h>
#include <hip/hip_bf16.h>
#include <stdint.h>

#define BB 4
#define TT 2048
#define DD 1024
#define HH 16
#define MTOK (BB*TT)
#define NQ 4096            // q|k|v|g concat width
#define NW (NQ+128)        // wcat rows incl. small-proj block
#define TC 32              // scan chunk length
#define NC (TT/TC)         // 64 chunks
#define BH (BB*HH)         // 64
#define ROWT (16*NQ)       // elements per 16-row blocked stripe

typedef __bf16 bf16x8 __attribute__((ext_vector_type(8)));
typedef float f32x4 __attribute__((ext_vector_type(4)));

__device__ __forceinline__ uint16_t f2bf(float f){
  uint32_t u = __float_as_uint(f);
  u += 0x7fffu + ((u >> 16) & 1u);
  return (uint16_t)(u >> 16);
}
__device__ __forceinline__ float bf2f(uint32_t h){ return __uint_as_float(h << 16); }
// sigmoid via fast exp + raw v_rcp_f32 (1 ulp) -- avoids precise-div expansion
__device__ __forceinline__ float sigm(float z){
  return __builtin_amdgcn_rcpf(1.f + __expf(-z));
}

__device__ __forceinline__ void gll16(const uint16_t* src, uint16_t* dst){
  __builtin_amdgcn_global_load_lds(
      (const __attribute__((address_space(1))) void*)src,
      (__attribute__((address_space(3))) void*)dst, 16, 0, 0);
}
// extract bf16 element e (static) from a uint4 (8 bf16)
__device__ __forceinline__ float bfel(const uint4& v, int e){
  uint32_t wrd = ((e>>1)==0) ? v.x : ((e>>1)==1) ? v.y : ((e>>1)==2) ? v.z : v.w;
  return bf2f((e&1) ? (wrd >> 16) : (wrd & 0xffffu));
}

// ---------------- prep: pure casts (R13-exact) ----------------
__global__ __launch_bounds__(256) void prep_kernel(
    const float* __restrict__ x,
    const float* __restrict__ Wq, const float* __restrict__ Wk,
    const float* __restrict__ Wv, const float* __restrict__ Wg,
    const float* __restrict__ Wo,
    const float* __restrict__ Wb, const float* __restrict__ Wfd,
    const float* __restrict__ Wsd,
    uint16_t* __restrict__ wcat, uint16_t* __restrict__ wob,
    uint16_t* __restrict__ xb)
{
  const int bx = blockIdx.x;
  if (bx < 5120){
    int i = bx * 256 + threadIdx.x;      // float4 index; 262144 per weight
    int wsel = i >> 18;
    int loc = i & 262143;
    const float* src = (wsel == 0) ? Wq : (wsel == 1) ? Wk : (wsel == 2) ? Wv : (wsel == 3) ? Wg : Wo;
    uint16_t* dst = (wsel < 4) ? (wcat + (size_t)wsel * DD * DD) : wob;
    float4 v = ((const float4*)src)[loc];
    ushort4 o;
    o.x = f2bf(v.x); o.y = f2bf(v.y); o.z = f2bf(v.z); o.w = f2bf(v.w);
    ((ushort4*)dst)[loc] = o;
  } else if (bx < 9216){
    int base = (bx - 5120) * 512 + threadIdx.x;
    #pragma unroll
    for (int rep = 0; rep < 2; rep++){
      int loc = base + rep * 256;
      float4 v = ((const float4*)x)[loc];
      ushort4 o;
      o.x = f2bf(v.x); o.y = f2bf(v.y); o.z = f2bf(v.z); o.w = f2bf(v.w);
      ((ushort4*)xb)[loc] = o;
    }
  } else {
    int u = (bx - 9216) * 256 + threadIdx.x;   // 4-elem unit; 256 units/row
    int row = u >> 8;
    int cidx = (u & 255) * 4;
    ushort4 o = {0, 0, 0, 0};
    if (row < 48){
      const float* src = (row < 16) ? (Wb + (size_t)row * DD)
                       : (row < 32) ? (Wfd + (size_t)(row - 16) * DD)
                                    : (Wsd + (size_t)(row - 32) * DD);
      float4 v = *(const float4*)(src + cidx);
      o.x = f2bf(v.x); o.y = f2bf(v.y); o.z = f2bf(v.z); o.w = f2bf(v.w);
    }
    *(ushort4*)(wcat + (size_t)(NQ + row) * DD + cidx) = o;
  }
}

// =============== 256x256 2-phase GEMM for qkvg (barrier-minimized pipeline) ===============
// X:[8192][1024], W:[4096][1024] bf16 row-major. 512 thr = 8 waves (2M x 4N),
// per-wave 128x64 = acc[8][4]. K-step 64 as two K-halves of 32.
// LDS = 2dbuf x 2half x [256][32] x (A,B) = 128 KiB.
// Per phase (one per K-half): {12 ds_read (a[8]+b[4]) || 4 gll stage -> lgkm0
// -> setprio 32-MFMA cluster -> counted vmcnt(4) -> ONE s_barrier}.
// 2 barriers per K-step (vs 8 in the 4-phase R14 port) -- attacks the measured
// 47% dual-pipe-idle barrier overhead (m233 mechanism).
// Ledger (per-wave outstanding glls): phase start 4 -> issue 4 -> 8 ->
// vmcnt(4) drains exactly the unit the NEXT phase reads; barrier publishes all
// waves' residency. Never vmcnt(0) except the tail step.
// Correctness of 1 barrier/phase: reads touch only buf, stages only nb; a
// wave's reads are complete at its lgkm0 (pre-MFMA), so phase-end barrier
// separates them from the opposite buffer's overwrite one step later.
// Quarter swizzle physQ = q ^ ((row>>1)&3), inverse on global source (rule 21).
__global__ __launch_bounds__(512, 2) void gemm256_qkvg(
    const uint16_t* __restrict__ X, const uint16_t* __restrict__ W,
    uint16_t* __restrict__ Y)
{
  constexpr int K = DD;
  constexpr int NT = K / 64;
  constexpr int HSZ = 8192;                       // u16 per [256][32] half
  __shared__ __align__(16) uint16_t sA[2][2][HSZ];
  __shared__ __align__(16) uint16_t sB[2][2][HSZ];

  const int tid = threadIdx.x;
  const int m0 = blockIdx.y * 256, n0 = blockIdx.x * 256;
  const int l = tid & 63, w = tid >> 6;
  const int wr = w >> 2, wc = w & 3;
  const int g = l >> 4, r16 = l & 15;

  // staging: chunk c (16B) of a half: row=c>>2, physQ=c&3, logQ=(c&3)^((c>>3)&3)
  const int c1 = tid + 512;
  const int r0 = tid >> 2, q0 = (tid & 3) ^ ((tid >> 3) & 3);
  const int r1 = c1 >> 2,  q1 = (c1 & 3) ^ ((c1 >> 3) & 3);
  const uint16_t* pA0 = X + (size_t)(m0 + r0) * K + q0 * 8;
  const uint16_t* pA1 = X + (size_t)(m0 + r1) * K + q1 * 8;
  const uint16_t* pB0 = W + (size_t)(n0 + r0) * K + q0 * 8;
  const uint16_t* pB1 = W + (size_t)(n0 + r1) * K + q1 * 8;
  const int d0 = w * 512, d1 = 4096 + w * 512;    // wave-uniform LDS u16 offs

  // frag read offsets within a half (u16): row*32 + (g^((r16>>1)&3))*8
  const int fsw = (g ^ ((r16 >> 1) & 3)) * 8;
  int roA[8], roB[4];
  #pragma unroll
  for (int mi = 0; mi < 8; mi++) roA[mi] = (wr * 128 + mi * 16 + r16) * 32 + fsw;
  #pragma unroll
  for (int ni = 0; ni < 4; ni++) roB[ni] = (wc * 64 + ni * 16 + r16) * 32 + fsw;

  f32x4 acc[8][4];
  #pragma unroll
  for (int i = 0; i < 8; i++)
    #pragma unroll
    for (int j = 0; j < 4; j++) acc[i][j] = (f32x4){0.f, 0.f, 0.f, 0.f};

  // prologue: stage tile0's 4 units (A0,B0,A1,B1); h0 resident, h1 in flight
  gll16(pA0,      &sA[0][0][d0]); gll16(pA1,      &sA[0][0][d1]);
  gll16(pB0,      &sB[0][0][d0]); gll16(pB1,      &sB[0][0][d1]);
  gll16(pA0 + 32, &sA[0][1][d0]); gll16(pA1 + 32, &sA[0][1][d1]);
  gll16(pB0 + 32, &sB[0][1][d0]); gll16(pB1 + 32, &sB[0][1][d1]);
  asm volatile("s_waitcnt vmcnt(4)" ::: "memory");
  __builtin_amdgcn_sched_barrier(0);
  __builtin_amdgcn_s_barrier();

  #pragma unroll 1
  for (int t = 0; t < NT; ++t){
    const int buf = t & 1, nb = buf ^ 1;
    const bool st = (t + 1 < NT);
    const int kof = (t + 1) * 64;
    bf16x8 a[8], b[4];

    // ---- phase A: half0 compute; stage A0,B0[t+1] ----
    #pragma unroll
    for (int mi = 0; mi < 8; mi++) a[mi] = *(const bf16x8*)&sA[buf][0][roA[mi]];
    #pragma unroll
    for (int ni = 0; ni < 4; ni++) b[ni] = *(const bf16x8*)&sB[buf][0][roB[ni]];
    if (st){
      gll16(pA0 + kof, &sA[nb][0][d0]); gll16(pA1 + kof, &sA[nb][0][d1]);
      gll16(pB0 + kof, &sB[nb][0][d0]); gll16(pB1 + kof, &sB[nb][0][d1]);
    }
    asm volatile("s_waitcnt lgkmcnt(0)" ::: "memory");
    __builtin_amdgcn_sched_barrier(0);
    __builtin_amdgcn_s_setprio(1);
    #pragma unroll
    for (int mi = 0; mi < 8; mi++){
      acc[mi][0] = __builtin_amdgcn_mfma_f32_16x16x32_bf16(a[mi], b[0], acc[mi][0], 0, 0, 0);
      acc[mi][1] = __builtin_amdgcn_mfma_f32_16x16x32_bf16(a[mi], b[1], acc[mi][1], 0, 0, 0);
      acc[mi][2] = __builtin_amdgcn_mfma_f32_16x16x32_bf16(a[mi], b[2], acc[mi][2], 0, 0, 0);
      acc[mi][3] = __builtin_amdgcn_mfma_f32_16x16x32_bf16(a[mi], b[3], acc[mi][3], 0, 0, 0);
    }
    __builtin_amdgcn_s_setprio(0);
    if (st) asm volatile("s_waitcnt vmcnt(4)" ::: "memory");   // A1,B1[t] resident
    else    asm volatile("s_waitcnt vmcnt(0)" ::: "memory");
    __builtin_amdgcn_sched_barrier(0);
    __builtin_amdgcn_s_barrier();                              // h1 published

    // ---- phase B: half1 compute; stage A1,B1[t+1] ----
    #pragma unroll
    for (int mi = 0; mi < 8; mi++) a[mi] = *(const bf16x8*)&sA[buf][1][roA[mi]];
    #pragma unroll
    for (int ni = 0; ni < 4; ni++) b[ni] = *(const bf16x8*)&sB[buf][1][roB[ni]];
    if (st){
      gll16(pA0 + kof + 32, &sA[nb][1][d0]); gll16(pA1 + kof + 32, &sA[nb][1][d1]);
      gll16(pB0 + kof + 32, &sB[nb][1][d0]); gll16(pB1 + kof + 32, &sB[nb][1][d1]);
    }
    asm volatile("s_waitcnt lgkmcnt(0)" ::: "memory");
    __builtin_amdgcn_sched_barrier(0);
    __builtin_amdgcn_s_setprio(1);
    #pragma unroll
    for (int mi = 0; mi < 8; mi++){
      acc[mi][0] = __builtin_amdgcn_mfma_f32_16x16x32_bf16(a[mi], b[0], acc[mi][0], 0, 0, 0);
      acc[mi][1] = __builtin_amdgcn_mfma_f32_16x16x32_bf16(a[mi], b[1], acc[mi][1], 0, 0, 0);
      acc[mi][2] = __builtin_amdgcn_mfma_f32_16x16x32_bf16(a[mi], b[2], acc[mi][2], 0, 0, 0);
      acc[mi][3] = __builtin_amdgcn_mfma_f32_16x16x32_bf16(a[mi], b[3], acc[mi][3], 0, 0, 0);
    }
    __builtin_amdgcn_s_setprio(0);
    if (st) asm volatile("s_waitcnt vmcnt(4)" ::: "memory");   // A0,B0[t+1] resident
    else    asm volatile("s_waitcnt vmcnt(0)" ::: "memory");
    __builtin_amdgcn_sched_barrier(0);
    __builtin_amdgcn_s_barrier();                              // next h0 published
  }

  // epilogue: C/D col=lane&15, row=(lane>>4)*4+reg; blocked store, 8B/lane/frag
  const bool dosig = (n0 >= 3 * DD);
  #pragma unroll
  for (int mi = 0; mi < 8; ++mi){
    const int R0 = m0 + wr * 128 + mi * 16;
    const size_t rbase = (size_t)(R0 >> 4) * ROWT;
    #pragma unroll
    for (int ni = 0; ni < 4; ++ni){
      const int C0 = n0 + wc * 64 + ni * 16;
      f32x4 v = acc[mi][ni];
      float o[4];
      #pragma unroll
      for (int r = 0; r < 4; r++){
        float xx = v[r];
        o[r] = dosig ? sigm(xx) : xx * sigm(xx);
      }
      uint2 pk;
      pk.x = (uint32_t)f2bf(o[0]) | ((uint32_t)f2bf(o[1]) << 16);
      pk.y = (uint32_t)f2bf(o[2]) | ((uint32_t)f2bf(o[3]) << 16);
      size_t off = rbase + (size_t)(C0 >> 4) * 256 + (size_t)r16 * 16 + g * 4;
      *(uint2*)(Y + off) = pk;
    }
  }
}

// =============== 128x128 GEMM, BK=64, m97 2-barrier structure (R13-exact) ===============
// MODE 1: plain f32 row-major out. MODE 2: small-proj -> sc f32 [3][B][H][T].
template<int MODE>
__global__ __launch_bounds__(256) void gemm128(
    const uint16_t* __restrict__ X, const uint16_t* __restrict__ W,
    uint16_t* __restrict__ Y, float* __restrict__ Yf,
    const float* __restrict__ bfd, const float* __restrict__ bsd,
    float* __restrict__ scp, int N, int K)
{
  __shared__ __align__(16) uint16_t lA[128 * 64];
  __shared__ __align__(16) uint16_t lB[128 * 64];
  const int tid = threadIdx.x;
  const int m0 = blockIdx.y * 128, n0 = blockIdx.x * 128;
  const int l = tid & 63, w = tid >> 6;
  const int wr = w >> 1, wc = w & 1;
  const int g = l >> 4, r16 = l & 15;

  const uint16_t* srcA[4];
  const uint16_t* srcB[4];
  uint16_t* dstA[4];
  uint16_t* dstB[4];
  #pragma unroll
  for (int n = 0; n < 4; n++){
    int p = n * 256 + tid;
    int row = p >> 3;
    int cq = (p & 7) ^ (row & 7);
    srcA[n] = X + (size_t)(m0 + row) * K + cq * 8;
    srcB[n] = W + (size_t)(n0 + row) * K + cq * 8;
    int basechunk = n * 256 + (tid & ~63);
    dstA[n] = lA + basechunk * 8;
    dstB[n] = lB + basechunk * 8;
  }

  int roA[4][2], roB[4][2];
  #pragma unroll
  for (int i = 0; i < 4; i++)
    #pragma unroll
    for (int ks = 0; ks < 2; ks++){
      roA[i][ks] = (wr * 64 + i * 16 + r16) * 64 + ((ks * 4 + g) ^ (r16 & 7)) * 8;
      roB[i][ks] = (wc * 64 + i * 16 + r16) * 64 + ((ks * 4 + g) ^ (r16 & 7)) * 8;
    }

  const bool doMfma = (MODE != 2) || (wc == 0);
  const int nLim = (MODE == 2) ? 3 : 4;

  f32x4 acc[4][4];
  #pragma unroll
  for (int i = 0; i < 4; i++)
    #pragma unroll
    for (int j = 0; j < 4; j++) acc[i][j] = (f32x4){0.f, 0.f, 0.f, 0.f};

  for (int kt = 0; kt < K; kt += 64){
    __syncthreads();
    #pragma unroll
    for (int n = 0; n < 4; n++){
      gll16(srcA[n] + kt, dstA[n]);
      gll16(srcB[n] + kt, dstB[n]);
    }
    __syncthreads();

    if (doMfma){
      #pragma unroll
      for (int ks = 0; ks < 2; ks++){
        bf16x8 af[4], bw[4];
        #pragma unroll
        for (int mi = 0; mi < 4; mi++) af[mi] = *(const bf16x8*)(lA + roA[mi][ks]);
        #pragma unroll
        for (int ni = 0; ni < nLim; ni++) bw[ni] = *(const bf16x8*)(lB + roB[ni][ks]);
        #pragma unroll
        for (int mi = 0; mi < 4; mi++)
          #pragma unroll
          for (int ni = 0; ni < nLim; ni++)
            acc[mi][ni] = __builtin_amdgcn_mfma_f32_16x16x32_bf16(af[mi], bw[ni], acc[mi][ni], 0, 0, 0);
      }
    }
  }

  if (MODE == 1){
    #pragma unroll
    for (int mi = 0; mi < 4; mi++){
      #pragma unroll
      for (int ni = 0; ni < 4; ni++){
        int rg = m0 + wr * 64 + mi * 16 + g * 4;
        int cg = n0 + wc * 64 + ni * 16 + r16;
        #pragma unroll
        for (int r = 0; r < 4; r++)
          Yf[(size_t)(rg + r) * N + cg] = acc[mi][ni][r];
      }
    }
  } else {
    if (wc == 0){
      #pragma unroll
      for (int ni = 0; ni < 3; ni++){
        const int grp = ni;
        const int h = r16;
        const float bias = (grp == 0) ? 0.f : (grp == 1) ? bfd[h] : bsd[h];
        #pragma unroll
        for (int mi = 0; mi < 4; mi++){
          const int R0 = m0 + wr * 64 + mi * 16 + g * 4;
          const int b = R0 >> 11, t = R0 & (TT - 1);
          f32x4 v = acc[mi][ni];
          float4 o;
          o.x = sigm(v[0] + bias);
          o.y = sigm(v[1] + bias);
          o.z = sigm(v[2] + bias);
          o.w = sigm(v[3] + bias);
          *(float4*)(scp + (((size_t)grp * BB + b) * HH + h) * TT + t) = o;
        }
      }
    }
  }
}

// ---------------- chunked scan over blocked qkvg (R13-exact) ----------------
__global__ __launch_bounds__(64) void scan_partA(
    const uint16_t* __restrict__ qkvg, const float* __restrict__ sc,
    float* __restrict__ Lst, float4* __restrict__ Pm)
{
  int j = blockIdx.x, bh = blockIdx.y;
  int b = bh >> 4, h = bh & 15;
  int c = threadIdx.x;
  const int ci = c & 15;
  const size_t tc_k = (size_t)((DD     + h * 64 + c) >> 4) * 256 + ci * 16;
  const size_t tc_v = (size_t)((2 * DD + h * 64 + c) >> 4) * 256 + ci * 16;
  const float* bet = sc + ((size_t)(0 * BB + b) * HH + h) * TT + j * TC;
  const float* fdp = sc + ((size_t)(1 * BB + b) * HH + h) * TT + j * TC;
  const float* sdp = sc + ((size_t)(2 * BB + b) * HH + h) * TT + j * TC;

  float sf = 0.f, ss = 0.f;
  float p00 = 1.f, p01 = 0.f, p10 = 0.f, p11 = 1.f;
  #pragma unroll
  for (int t16 = 0; t16 < 2; ++t16){
    int R0 = b * TT + j * TC + t16 * 16;
    size_t tb = (size_t)(R0 >> 4) * ROWT;
    uint4 kl = *(const uint4*)(qkvg + tb + tc_k);
    uint4 kh = *(const uint4*)(qkvg + tb + tc_k + 8);
    uint4 vl = *(const uint4*)(qkvg + tb + tc_v);
    uint4 vh = *(const uint4*)(qkvg + tb + tc_v + 8);
    const float* bt = bet + t16 * 16;
    const float* ft = fdp + t16 * 16;
    const float* st = sdp + t16 * 16;
    #pragma unroll
    for (int u = 0; u < 16; ++u){
      float kv = (u < 8) ? bfel(kl, u) : bfel(kh, u - 8);
      float vv = (u < 8) ? bfel(vl, u) : bfel(vh, u - 8);
      float btv = bt[u], f = ft[u], s = st[u];
      float uu = 1.05f * btv * kv * vv;
      float bq = 0.05f * s, cq = 0.05f * f;
      float nf = f * sf + bq * ss + uu;
      float ns = cq * sf + s * ss + uu;
      sf = nf; ss = ns;
      float q00 = f * p00 + bq * p10, q01 = f * p01 + bq * p11;
      float q10 = cq * p00 + s * p10, q11 = cq * p01 + s * p11;
      p00 = q00; p01 = q01; p10 = q10; p11 = q11;
    }
  }
  size_t base = ((size_t)bh * NC + j) * 2;
  Lst[(base + 0) * 64 + c] = sf;
  Lst[(base + 1) * 64 + c] = ss;
  if (c == 0) Pm[(size_t)bh * NC + j] = make_float4(p00, p01, p10, p11);
}

__global__ __launch_bounds__(64) void scan_partC(
    const uint16_t* __restrict__ qkvg, const float* __restrict__ sc,
    const float* __restrict__ Lst, const float4* __restrict__ Pm,
    uint16_t* __restrict__ og)
{
  __shared__ uint16_t ot[16 * 64];
  int j = blockIdx.x, bh = blockIdx.y;
  int b = bh >> 4, h = bh & 15;
  int c = threadIdx.x;
  const int ci = c & 15;

  float sf = 0.f, ss = 0.f;
  for (int i = 0; i < j; ++i){
    size_t pbase = ((size_t)bh * NC + i) * 2;
    float lf = Lst[(pbase + 0) * 64 + c];
    float ls = Lst[(pbase + 1) * 64 + c];
    float4 P = Pm[(size_t)bh * NC + i];
    float nf = P.x * sf + P.y * ss + lf;
    float ns = P.z * sf + P.w * ss + ls;
    sf = nf; ss = ns;
  }

  const size_t tc_q = (size_t)((         h * 64 + c) >> 4) * 256 + ci * 16;
  const size_t tc_k = (size_t)((DD     + h * 64 + c) >> 4) * 256 + ci * 16;
  const size_t tc_v = (size_t)((2 * DD + h * 64 + c) >> 4) * 256 + ci * 16;
  const size_t tc_g = (size_t)((3 * DD + h * 64 + c) >> 4) * 256 + ci * 16;
  const float* bet = sc + ((size_t)(0 * BB + b) * HH + h) * TT + j * TC;
  const float* fdp = sc + ((size_t)(1 * BB + b) * HH + h) * TT + j * TC;
  const float* sdp = sc + ((size_t)(2 * BB + b) * HH + h) * TT + j * TC;

  #pragma unroll
  for (int t16 = 0; t16 < 2; ++t16){
    int R0 = b * TT + j * TC + t16 * 16;
    size_t tb = (size_t)(R0 >> 4) * ROWT;
    uint4 ql = *(const uint4*)(qkvg + tb + tc_q);
    uint4 qh = *(const uint4*)(qkvg + tb + tc_q + 8);
    uint4 kl = *(const uint4*)(qkvg + tb + tc_k);
    uint4 kh = *(const uint4*)(qkvg + tb + tc_k + 8);
    uint4 vl = *(const uint4*)(qkvg + tb + tc_v);
    uint4 vh = *(const uint4*)(qkvg + tb + tc_v + 8);
    uint4 gl = *(const uint4*)(qkvg + tb + tc_g);
    uint4 gh = *(const uint4*)(qkvg + tb + tc_g + 8);
    const float* bt = bet + t16 * 16;
    const float* ft = fdp + t16 * 16;
    const float* st = sdp + t16 * 16;
    #pragma unroll
    for (int u = 0; u < 16; ++u){
      float qv = (u < 8) ? bfel(ql, u) : bfel(qh, u - 8);
      float kv = (u < 8) ? bfel(kl, u) : bfel(kh, u - 8);
      float vv = (u < 8) ? bfel(vl, u) : bfel(vh, u - 8);
      float gv = (u < 8) ? bfel(gl, u) : bfel(gh, u - 8);
      float btv = bt[u], f = ft[u], s = st[u];
      sf *= f; ss *= s;
      float o = 0.5f * qv * (sf + ss);
      float uu = btv * kv * vv;
      sf += uu; ss += uu;
      float nf = sf + 0.05f * ss, ns = ss + 0.05f * sf;
      sf = nf; ss = ns;
      ot[u * 64 + c] = f2bf(o * gv);
    }
    __syncthreads();
    {
      int u0 = c >> 3, c8 = c & 7;
      uint4 d0 = *(const uint4*)&ot[u0 * 64 + c8 * 8];
      uint4 d1 = *(const uint4*)&ot[(u0 + 8) * 64 + c8 * 8];
      uint16_t* ob = og + (size_t)R0 * DD + h * 64 + c8 * 8;
      *(uint4*)(ob + (size_t)u0 * DD) = d0;
      *(uint4*)(ob + (size_t)(u0 + 8) * DD) = d1;
    }
    __syncthreads();
  }
}

extern "C" void kernel_launch(void* const* d_in, const int* in_sizes, int n_in,
                              void* d_out, int out_size, void* d_ws, size_t ws_size,
                              hipStream_t stream)
{
  const float* x   = (const float*)d_in[0];
  const float* Wq  = (const float*)d_in[1];
  const float* Wk  = (const float*)d_in[2];
  const float* Wv  = (const float*)d_in[3];
  const float* Wo  = (const float*)d_in[4];
  const float* Wb  = (const float*)d_in[5];
  const float* Wfd = (const float*)d_in[6];
  const float* bfd = (const float*)d_in[7];
  const float* Wsd = (const float*)d_in[8];
  const float* bsd = (const float*)d_in[9];
  const float* Wg  = (const float*)d_in[10];
  float* out = (float*)d_out;

  char* ws = (char*)d_ws;
  size_t off = 0;
  auto alloc = [&](size_t bytes) -> void* {
    void* p = ws + off;
    off += (bytes + 255) & ~(size_t)255;
    return p;
  };

  uint16_t* xb   = (uint16_t*)alloc((size_t)MTOK * DD * 2);   // doubles as ogb later
  uint16_t* wcat = (uint16_t*)alloc((size_t)NW * DD * 2);     // Wq|Wk|Wv|Wg|small(128)
  uint16_t* wob  = (uint16_t*)alloc((size_t)DD * DD * 2);
  uint16_t* qkvg = (uint16_t*)alloc((size_t)MTOK * NQ * 2);   // blocked layout
  float*    sc   = (float*)alloc((size_t)3 * BB * HH * TT * 4);
  float*    Lst  = (float*)alloc((size_t)BH * NC * 2 * 64 * 4);
  float4*   Pm   = (float4*)alloc((size_t)BH * NC * 16);
  uint16_t* ogb  = xb;

  // prep: all casts (weights, x, small-proj weight block) in one dispatch
  prep_kernel<<<9344, 256, 0, stream>>>(
      x, Wq, Wk, Wv, Wg, Wo, Wb, Wfd, Wsd, wcat, wob, xb);

  // small projections: [8192,1024] @ [128,1024]^T -> sc (f32), tiny MFMA GEMM
  dim3 gp(1, MTOK / 128);
  gemm128<2><<<gp, 256, 0, stream>>>(xb, wcat + (size_t)NQ * DD, nullptr, nullptr,
                                     bfd, bsd, sc, NQ, DD);

  // fused q|k|v|g GEMM: [8192,1024] @ [4096,1024]^T -> blocked bf16 (2-phase 256^2)
  dim3 gq(NQ / 256, MTOK / 256);
  gemm256_qkvg<<<gq, 512, 0, stream>>>(xb, wcat, qkvg);

  // chunked scan: partA (local) then partC (lookback + replay)
  dim3 gs(NC, BH);
  scan_partA<<<gs, 64, 0, stream>>>(qkvg, sc, Lst, Pm);
  scan_partC<<<gs, 64, 0, stream>>>(qkvg, sc, Lst, Pm, ogb);

  // out = (o*g) @ Wo^T, fp32 row-major out (2D grid, 8%8==0 aligned)
  dim3 go(DD / 128, MTOK / 128);
  gemm128<1><<<go, 256, 0, stream>>>(ogb, wob, nullptr, out, bfd, bsd, nullptr, DD, DD);
}